// Round 1
// baseline (1083.316 us; speedup 1.0000x reference)
//
#include <hip/hip_runtime.h>
#include <math.h>

#define HN 8
#define POSN 16
#define SN 33
#define HALF_SN 16
#define CDIM 1024
#define DHEAD 128
#define LDIM 4096
#define BDIM 2
#define NTOK (BDIM * LDIM)

__device__ __forceinline__ float sigf(float x) { return 1.0f / (1.0f + expf(-x)); }
__device__ __forceinline__ float siluf(float x) { return x / (1.0f + expf(-x)); }

// ---------------------------------------------------------------------------
// Kernel A: per-token projections.
//   wave = silu(x @ wave_w + wave_b)  (24 cols) -> freq/phase/decay + means
//   q    = silu(x @ query_w + query_b) (128 cols)
// One block per token; x row staged in LDS; threads 0..151 each own a column.
// ---------------------------------------------------------------------------
__global__ __launch_bounds__(256) void waveq_kernel(
    const float* __restrict__ x,
    const float* __restrict__ wave_w, const float* __restrict__ wave_b,
    const float* __restrict__ query_w, const float* __restrict__ query_b,
    float* __restrict__ q_out, float* __restrict__ freq_out,
    float* __restrict__ decay_out, float* __restrict__ favg_out,
    float* __restrict__ pavg_out)
{
    const int t = blockIdx.x;
    const int tid = threadIdx.x;
    __shared__ float xs[CDIM];
    __shared__ float wpre[24];   // silu(wave pre-act)
    __shared__ float fsh[HN], psh[HN];

    const float* xrow = x + (size_t)t * CDIM;
    for (int i = tid; i < CDIM; i += 256) xs[i] = xrow[i];
    __syncthreads();

    if (tid < 152) {
        float acc;
        if (tid < 24) {
            acc = wave_b[tid];
            #pragma unroll 4
            for (int k = 0; k < CDIM; ++k) acc += xs[k] * wave_w[k * 24 + tid];
            wpre[tid] = siluf(acc);
        } else {
            const int j = tid - 24;
            acc = query_b[j];
            #pragma unroll 4
            for (int k = 0; k < CDIM; ++k) acc += xs[k] * query_w[k * 128 + j];
            q_out[(size_t)t * 128 + j] = siluf(acc);
        }
    }
    __syncthreads();

    if (tid < HN) {
        float f = sigf(wpre[tid]) * 15.0f + 1.0f;          // MAX_F - MIN_F = 15
        float p = tanhf(wpre[8 + tid]) * 16.0f;            // MAX_F
        float d = sigf(wpre[16 + tid]) * 9.5f + 0.5f;
        freq_out[(size_t)t * HN + tid] = f;
        decay_out[(size_t)t * HN + tid] = d;
        fsh[tid] = f; psh[tid] = p;
    }
    __syncthreads();
    if (tid == 0) {
        float fa = 0.f, pa = 0.f;
        for (int h = 0; h < HN; ++h) { fa += fsh[h]; pa += psh[h]; }
        favg_out[t] = fa * 0.125f;
        pavg_out[t] = pa * 0.125f;
    }
}

// ---------------------------------------------------------------------------
// Kernel B: adaptive conv. One block per token.
//   sample_idx/valid -> logits (q . silu(rel*key_w)) -> masked softmax * env
//   -> renormalize -> out[h,d] = sum_s w[h][s] * x[b, idx[s], h*128+d]
// ---------------------------------------------------------------------------
__global__ __launch_bounds__(256) void adaptconv_kernel(
    const float* __restrict__ x, const float* __restrict__ key_w,
    const float* __restrict__ q, const float* __restrict__ freq,
    const float* __restrict__ decay, const float* __restrict__ favg,
    const float* __restrict__ pavg, float* __restrict__ out)
{
    const int t = blockIdx.x;
    const int b = t / LDIM, l = t % LDIM;
    const int tid = threadIdx.x;

    __shared__ int   idx_s[SN];
    __shared__ float msk[SN];
    __shared__ float qs[128];
    __shared__ float kw[POSN];
    __shared__ float fr[HN], dc[HN];
    __shared__ float wgt[HN][SN];

    if (tid < 128) qs[tid] = q[(size_t)t * 128 + tid];
    if (tid < POSN) kw[tid] = key_w[tid];
    if (tid < HN) {
        fr[tid] = freq[(size_t)t * HN + tid];
        dc[tid] = decay[(size_t)t * HN + tid];
    }
    if (tid < SN) {
        float fa = favg[t], pa = pavg[t];
        float sp = (float)l + (float)(tid - HALF_SN) * fa + pa;
        bool v = (sp >= 0.0f) && (sp < (float)LDIM);
        int si = (int)sp;                 // trunc toward zero, matches astype(int32)
        si = min(max(si, 0), LDIM - 1);
        idx_s[tid] = si;
        msk[tid] = v ? 1.0f : 0.0f;
    }
    __syncthreads();

    for (int task = tid; task < HN * SN; task += 256) {
        const int h = task / SN, s = task % SN;
        float rel = fabsf((float)(s - HALF_SN)) * fr[h];
        float acc = 0.0f;
        #pragma unroll
        for (int p = 0; p < POSN; ++p) {
            float kk = rel * kw[p];
            acc += qs[h * POSN + p] * siluf(kk);
        }
        float lg = 0.25f * acc;           // SCALE = POS^-0.5
        if (msk[s] == 0.0f) lg = -1e30f;
        wgt[h][s] = lg;
    }
    __syncthreads();

    if (tid < HN) {
        const int h = tid;
        float m = -3.4e38f;
        for (int s = 0; s < SN; ++s) m = fmaxf(m, wgt[h][s]);
        float pexp[SN];
        float ssum = 0.0f;
        for (int s = 0; s < SN; ++s) { float e = expf(wgt[h][s] - m); pexp[s] = e; ssum += e; }
        float dci = fmaxf(dc[h], 0.1f);
        float wsum = 0.0f;
        for (int s = 0; s < SN; ++s) {
            float rel = fabsf((float)(s - HALF_SN)) * fr[h];
            float env = expf(-rel / dci);
            float wv = (pexp[s] / ssum) * env * msk[s];
            pexp[s] = wv; wsum += wv;
        }
        float inv = 1.0f / (wsum + 1e-8f);
        for (int s = 0; s < SN; ++s) wgt[h][s] = pexp[s] * inv;
    }
    __syncthreads();

    const float* xb = x + (size_t)b * LDIM * CDIM;
    for (int c = tid; c < CDIM; c += 256) {
        const int h = c >> 7;
        float acc = 0.0f;
        for (int s = 0; s < SN; ++s)
            acc += wgt[h][s] * xb[(size_t)idx_s[s] * CDIM + c];
        out[(size_t)t * CDIM + c] = acc;
    }
}

// ---------------------------------------------------------------------------
// Tiled fp32 GEMM with fused epilogue. 64x64 tile, BK=16, 256 thr, 4x4/thread.
// MODE 0: silu(acc + bias[col])
// MODE 1: sigmoid(acc + bias[col]) * mul[row*N+col]
// MODE 2: silu(acc)
// M,N,K all divisible by tile dims for our shapes — no bounds checks.
// ---------------------------------------------------------------------------
template <int MODE>
__global__ __launch_bounds__(256) void gemm_epi(
    const float* __restrict__ A, const float* __restrict__ B,
    const float* __restrict__ bias, const float* __restrict__ mul,
    float* __restrict__ C, int M, int N, int K)
{
    const int tid = threadIdx.x;
    const int bm = blockIdx.x * 64, bn = blockIdx.y * 64;
    __shared__ float As[16][65];
    __shared__ float Bs[16][65];
    float acc[4][4];
    #pragma unroll
    for (int i = 0; i < 4; ++i)
        #pragma unroll
        for (int j = 0; j < 4; ++j) acc[i][j] = 0.0f;

    const int tr = tid >> 4, tc = tid & 15;

    for (int k0 = 0; k0 < K; k0 += 16) {
        #pragma unroll
        for (int e = tid; e < 1024; e += 256) {
            int m = e >> 4, kk = e & 15;
            As[kk][m] = A[(size_t)(bm + m) * K + k0 + kk];
        }
        #pragma unroll
        for (int e = tid; e < 1024; e += 256) {
            int kk = e >> 6, n = e & 63;
            Bs[kk][n] = B[(size_t)(k0 + kk) * N + bn + n];
        }
        __syncthreads();
        #pragma unroll
        for (int kk = 0; kk < 16; ++kk) {
            float a[4], bv[4];
            #pragma unroll
            for (int i = 0; i < 4; ++i) a[i] = As[kk][tr * 4 + i];
            #pragma unroll
            for (int j = 0; j < 4; ++j) bv[j] = Bs[kk][tc * 4 + j];
            #pragma unroll
            for (int i = 0; i < 4; ++i)
                #pragma unroll
                for (int j = 0; j < 4; ++j) acc[i][j] += a[i] * bv[j];
        }
        __syncthreads();
    }

    #pragma unroll
    for (int i = 0; i < 4; ++i) {
        const int row = bm + tr * 4 + i;
        #pragma unroll
        for (int j = 0; j < 4; ++j) {
            const int col = bn + tc * 4 + j;
            float v = acc[i][j];
            if (MODE == 0) v = siluf(v + bias[col]);
            if (MODE == 1) v = sigf(v + bias[col]) * mul[(size_t)row * N + col];
            if (MODE == 2) v = siluf(v);
            C[(size_t)row * N + col] = v;
        }
    }
}

// ---------------------------------------------------------------------------
extern "C" void kernel_launch(void* const* d_in, const int* in_sizes, int n_in,
                              void* d_out, int out_size, void* d_ws, size_t ws_size,
                              hipStream_t stream)
{
    const float* x       = (const float*)d_in[0];
    const float* wave_w  = (const float*)d_in[1];
    const float* wave_b  = (const float*)d_in[2];
    const float* query_w = (const float*)d_in[3];
    const float* query_b = (const float*)d_in[4];
    const float* key_w   = (const float*)d_in[5];
    const float* out_w   = (const float*)d_in[6];
    const float* se1_w   = (const float*)d_in[7];
    const float* se1_b   = (const float*)d_in[8];
    const float* se2_w   = (const float*)d_in[9];
    const float* se2_b   = (const float*)d_in[10];

    float* ws = (float*)d_ws;
    float* q     = ws;                               // NTOK*128
    float* freq  = q     + (size_t)NTOK * 128;       // NTOK*8
    float* decay = freq  + (size_t)NTOK * HN;        // NTOK*8
    float* favg  = decay + (size_t)NTOK * HN;        // NTOK
    float* pavg  = favg  + (size_t)NTOK;             // NTOK
    float* conv  = pavg  + (size_t)NTOK;             // NTOK*1024
    float* tmp1  = conv  + (size_t)NTOK * CDIM;      // NTOK*256

    waveq_kernel<<<NTOK, 256, 0, stream>>>(x, wave_w, wave_b, query_w, query_b,
                                           q, freq, decay, favg, pavg);
    adaptconv_kernel<<<NTOK, 256, 0, stream>>>(x, key_w, q, freq, decay, favg,
                                               pavg, conv);
    // SE1: silu(conv @ se1_w + se1_b) -> tmp1  (8192x1024 @ 1024x256)
    gemm_epi<0><<<dim3(NTOK / 64, 256 / 64), 256, 0, stream>>>(
        conv, se1_w, se1_b, nullptr, tmp1, NTOK, 256, CDIM);
    // SE2: sigmoid(tmp1 @ se2_w + se2_b) * conv -> conv (in place, safe)
    gemm_epi<1><<<dim3(NTOK / 64, CDIM / 64), 256, 0, stream>>>(
        tmp1, se2_w, se2_b, conv, conv, NTOK, CDIM, 256);
    // OUT: silu(conv @ out_w) -> d_out  (8192x1024 @ 1024x1024)
    gemm_epi<2><<<dim3(NTOK / 64, CDIM / 64), 256, 0, stream>>>(
        conv, out_w, nullptr, nullptr, (float*)d_out, NTOK, CDIM, CDIM);
}

// Round 2
// 281.688 us; speedup vs baseline: 3.8458x; 3.8458x over previous
//
#include <hip/hip_runtime.h>
#include <math.h>

#define HN 8
#define POSN 16
#define SN 33
#define HALF_SN 16
#define CDIM 1024
#define LDIM 4096
#define BDIM 2
#define NTOK (BDIM * LDIM)

typedef unsigned short ushort_t;
typedef short short8 __attribute__((ext_vector_type(8)));
typedef float f32x4 __attribute__((ext_vector_type(4)));
struct alignas(8) US4 { unsigned short x, y, z, w; };

__device__ __forceinline__ float sigf(float x) { return 1.0f / (1.0f + expf(-x)); }
__device__ __forceinline__ float siluf(float x) { return x / (1.0f + expf(-x)); }
__device__ __forceinline__ unsigned short f2b(float f) {
    union { float f; unsigned u; } v; v.f = f;
    unsigned r = v.u + 0x7fffu + ((v.u >> 16) & 1u);   // RNE
    return (unsigned short)(r >> 16);
}

// ---------------------------------------------------------------------------
// Weight prep: in[K][N] fp32 -> out[N][K] bf16 (transposed, so GEMM B-frags
// are contiguous along K for ds_read_b128).
// ---------------------------------------------------------------------------
__global__ __launch_bounds__(256) void transcast(
    const float* __restrict__ in, unsigned short* __restrict__ out, int N, int K)
{
    __shared__ float tile[32][33];
    const int bn = blockIdx.x * 32, bk = blockIdx.y * 32;
    const int tx = threadIdx.x & 31, ty = threadIdx.x >> 5;
    #pragma unroll
    for (int yy = ty; yy < 32; yy += 8)
        tile[yy][tx] = in[(size_t)(bk + yy) * N + bn + tx];
    __syncthreads();
    #pragma unroll
    for (int yy = ty; yy < 32; yy += 8)
        out[(size_t)(bn + yy) * K + bk + tx] = f2b(tile[tx][yy]);
}

// ---------------------------------------------------------------------------
// Wave projection (24 cols), exact fp32 (protects the sample_idx int-trunc
// path from bf16 noise). Block = 8 tokens x 32 lanes (24 active).
// ---------------------------------------------------------------------------
__global__ __launch_bounds__(256) void wave_kernel(
    const float* __restrict__ x, const float* __restrict__ wave_w,
    const float* __restrict__ wave_b, float* __restrict__ freq,
    float* __restrict__ decay, float* __restrict__ favg, float* __restrict__ pavg)
{
    const int tid = threadIdx.x;
    const int tok = tid >> 5, col = tid & 31;
    const int t = blockIdx.x * 8 + tok;
    __shared__ float wsh[8][24];
    __shared__ float fsh[8][8], psh[8][8];

    if (col < 24) {
        float acc = wave_b[col];
        const float* xr = x + (size_t)t * CDIM;
        #pragma unroll 8
        for (int k = 0; k < CDIM; ++k) acc += xr[k] * wave_w[k * 24 + col];
        wsh[tok][col] = siluf(acc);
    }
    __syncthreads();
    if (col < 8) {
        float f = sigf(wsh[tok][col])      * 15.0f + 1.0f;
        float p = tanhf(wsh[tok][8 + col]) * 16.0f;
        float d = sigf(wsh[tok][16 + col]) * 9.5f + 0.5f;
        freq[(size_t)t * HN + col] = f;
        decay[(size_t)t * HN + col] = d;
        fsh[tok][col] = f; psh[tok][col] = p;
    }
    __syncthreads();
    if (col == 0) {
        float fa = 0.f, pa = 0.f;
        for (int h = 0; h < HN; ++h) { fa += fsh[tok][h]; pa += psh[tok][h]; }
        favg[t] = fa * 0.125f; pavg[t] = pa * 0.125f;
    }
}

// ---------------------------------------------------------------------------
// bf16 MFMA GEMM, 128x128 tile, BK=32, 4 waves (each 64x64 via 4x4 frags of
// 16x16x32). A: [M][K] fp32 (converted during staging) or bf16. B: [N][K]
// bf16 (pre-transposed). LDS rows padded +8 bf16 to spread banks.
// MODE 0: silu(acc+bias)->f32   MODE 1: silu(acc+bias)->bf16
// MODE 2: sigmoid(acc+bias)*mul->bf16   MODE 3: silu(acc)->f32
// ---------------------------------------------------------------------------
template <int MODE, bool A_BF16>
__global__ __launch_bounds__(256) void mfma_gemm(
    const void* __restrict__ Aptr, const unsigned short* __restrict__ Bt,
    const float* __restrict__ bias, const float* __restrict__ mul,
    void* __restrict__ Cptr, int M, int N, int K)
{
    __shared__ unsigned short As[128][40];
    __shared__ unsigned short Bs[128][40];

    const int tid = threadIdx.x;
    const int bm = blockIdx.x * 128, bn = blockIdx.y * 128;
    const int wid = tid >> 6, lane = tid & 63;
    const int wr = (wid >> 1) * 64, wc = (wid & 1) * 64;
    const int fm = lane & 15;          // row/col within 16x16 frag
    const int kg = (lane >> 4) * 8;    // k-group offset (8 contiguous k)

    const float* Af = (const float*)Aptr;
    const unsigned short* Ab = (const unsigned short*)Aptr;

    f32x4 acc[4][4];
    #pragma unroll
    for (int i = 0; i < 4; ++i)
        #pragma unroll
        for (int j = 0; j < 4; ++j) acc[i][j] = (f32x4){0.f, 0.f, 0.f, 0.f};

    const int sr = tid >> 3;           // 0..31, +p*32 -> rows 0..127
    const int sk = (tid & 7) * 4;      // k offset within BK=32

    for (int k0 = 0; k0 < K; k0 += 32) {
        #pragma unroll
        for (int p = 0; p < 4; ++p) {
            const int r = sr + p * 32;
            if (A_BF16) {
                US4 h = *(const US4*)(Ab + (size_t)(bm + r) * K + k0 + sk);
                *(US4*)(&As[r][sk]) = h;
            } else {
                float4 v = *(const float4*)(Af + (size_t)(bm + r) * K + k0 + sk);
                US4 h; h.x = f2b(v.x); h.y = f2b(v.y); h.z = f2b(v.z); h.w = f2b(v.w);
                *(US4*)(&As[r][sk]) = h;
            }
            US4 hb = *(const US4*)(Bt + (size_t)(bn + r) * K + k0 + sk);
            *(US4*)(&Bs[r][sk]) = hb;
        }
        __syncthreads();

        short8 a[4], b[4];
        #pragma unroll
        for (int i = 0; i < 4; ++i) a[i] = *(const short8*)(&As[wr + i * 16 + fm][kg]);
        #pragma unroll
        for (int j = 0; j < 4; ++j) b[j] = *(const short8*)(&Bs[wc + j * 16 + fm][kg]);
        #pragma unroll
        for (int i = 0; i < 4; ++i)
            #pragma unroll
            for (int j = 0; j < 4; ++j)
                acc[i][j] = __builtin_amdgcn_mfma_f32_16x16x32_bf16(a[i], b[j], acc[i][j], 0, 0, 0);
        __syncthreads();
    }

    // Epilogue. C/D layout: col = lane&15, row = (lane>>4)*4 + e  [m89-verified]
    float* Cf = (float*)Cptr;
    unsigned short* Cb = (unsigned short*)Cptr;
    #pragma unroll
    for (int i = 0; i < 4; ++i) {
        const int row0 = bm + wr + i * 16 + (lane >> 4) * 4;
        #pragma unroll
        for (int j = 0; j < 4; ++j) {
            const int col = bn + wc + j * 16 + fm;
            const float vb = (MODE == 3) ? 0.0f : bias[col];
            #pragma unroll
            for (int e = 0; e < 4; ++e) {
                const int row = row0 + e;
                float v = acc[i][j][e];
                if (MODE == 0 || MODE == 1) v = siluf(v + vb);
                if (MODE == 2) v = sigf(v + vb) * mul[(size_t)row * N + col];
                if (MODE == 3) v = siluf(v);
                if (MODE == 0 || MODE == 3) Cf[(size_t)row * N + col] = v;
                else                        Cb[(size_t)row * N + col] = f2b(v);
            }
        }
    }
}

// ---------------------------------------------------------------------------
// Adaptive conv. One block per token (unchanged math; float4 gather).
// ---------------------------------------------------------------------------
__global__ __launch_bounds__(256) void adaptconv_kernel(
    const float* __restrict__ x, const float* __restrict__ key_w,
    const float* __restrict__ q, const float* __restrict__ freq,
    const float* __restrict__ decay, const float* __restrict__ favg,
    const float* __restrict__ pavg, float* __restrict__ out)
{
    const int t = blockIdx.x;
    const int b = t / LDIM, l = t % LDIM;
    const int tid = threadIdx.x;

    __shared__ int   idx_s[SN];
    __shared__ float msk[SN];
    __shared__ float qs[128];
    __shared__ float kw[POSN];
    __shared__ float fr[HN], dc[HN];
    __shared__ float wgt[HN][SN];

    if (tid < 128) qs[tid] = q[(size_t)t * 128 + tid];
    if (tid < POSN) kw[tid] = key_w[tid];
    if (tid < HN) {
        fr[tid] = freq[(size_t)t * HN + tid];
        dc[tid] = decay[(size_t)t * HN + tid];
    }
    if (tid < SN) {
        float fa = favg[t], pa = pavg[t];
        float sp = (float)l + (float)(tid - HALF_SN) * fa + pa;
        bool v = (sp >= 0.0f) && (sp < (float)LDIM);
        int si = (int)sp;
        si = min(max(si, 0), LDIM - 1);
        idx_s[tid] = si;
        msk[tid] = v ? 1.0f : 0.0f;
    }
    __syncthreads();

    for (int task = tid; task < HN * SN; task += 256) {
        const int h = task / SN, s = task % SN;
        float rel = fabsf((float)(s - HALF_SN)) * fr[h];
        float acc = 0.0f;
        #pragma unroll
        for (int p = 0; p < POSN; ++p) acc += qs[h * POSN + p] * siluf(rel * kw[p]);
        float lg = 0.25f * acc;
        if (msk[s] == 0.0f) lg = -1e30f;
        wgt[h][s] = lg;
    }
    __syncthreads();

    if (tid < HN) {
        const int h = tid;
        float m = -3.4e38f;
        for (int s = 0; s < SN; ++s) m = fmaxf(m, wgt[h][s]);
        float pexp[SN];
        float ssum = 0.0f;
        for (int s = 0; s < SN; ++s) { float e = expf(wgt[h][s] - m); pexp[s] = e; ssum += e; }
        float dci = fmaxf(dc[h], 0.1f);
        float wsum = 0.0f;
        for (int s = 0; s < SN; ++s) {
            float rel = fabsf((float)(s - HALF_SN)) * fr[h];
            float wv = (pexp[s] / ssum) * expf(-rel / dci) * msk[s];
            pexp[s] = wv; wsum += wv;
        }
        float inv = 1.0f / (wsum + 1e-8f);
        for (int s = 0; s < SN; ++s) wgt[h][s] = pexp[s] * inv;
    }
    __syncthreads();

    const float* xb = x + (size_t)b * LDIM * CDIM;
    const int c4 = tid * 4;
    const int h = c4 >> 7;
    float ax = 0.f, ay = 0.f, az = 0.f, aw = 0.f;
    for (int s = 0; s < SN; ++s) {
        float w = wgt[h][s];
        float4 v = *(const float4*)(xb + (size_t)idx_s[s] * CDIM + c4);
        ax += w * v.x; ay += w * v.y; az += w * v.z; aw += w * v.w;
    }
    float4 o; o.x = ax; o.y = ay; o.z = az; o.w = aw;
    *(float4*)(out + (size_t)t * CDIM + c4) = o;
}

// ---------------------------------------------------------------------------
extern "C" void kernel_launch(void* const* d_in, const int* in_sizes, int n_in,
                              void* d_out, int out_size, void* d_ws, size_t ws_size,
                              hipStream_t stream)
{
    const float* x       = (const float*)d_in[0];
    const float* wave_w  = (const float*)d_in[1];
    const float* wave_b  = (const float*)d_in[2];
    const float* query_w = (const float*)d_in[3];
    const float* query_b = (const float*)d_in[4];
    const float* key_w   = (const float*)d_in[5];
    const float* out_w   = (const float*)d_in[6];
    const float* se1_w   = (const float*)d_in[7];
    const float* se1_b   = (const float*)d_in[8];
    const float* se2_w   = (const float*)d_in[9];
    const float* se2_b   = (const float*)d_in[10];

    char* wsb = (char*)d_ws;
    float* q        = (float*)wsb;                 wsb += (size_t)NTOK * 128 * 4;
    float* freq     = (float*)wsb;                 wsb += (size_t)NTOK * HN * 4;
    float* decay    = (float*)wsb;                 wsb += (size_t)NTOK * HN * 4;
    float* favg     = (float*)wsb;                 wsb += (size_t)NTOK * 4;
    float* pavg     = (float*)wsb;                 wsb += (size_t)NTOK * 4;
    float* conv     = (float*)wsb;                 wsb += (size_t)NTOK * CDIM * 4;
    unsigned short* tmp1_bf = (unsigned short*)wsb; wsb += (size_t)NTOK * 256 * 2;
    unsigned short* g_bf    = (unsigned short*)wsb; wsb += (size_t)NTOK * CDIM * 2;
    unsigned short* qw_bf   = (unsigned short*)wsb; wsb += (size_t)128 * CDIM * 2;
    unsigned short* se1w_bf = (unsigned short*)wsb; wsb += (size_t)256 * CDIM * 2;
    unsigned short* se2w_bf = (unsigned short*)wsb; wsb += (size_t)CDIM * 256 * 2;
    unsigned short* outw_bf = (unsigned short*)wsb; wsb += (size_t)CDIM * CDIM * 2;

    // Weight prep (transpose + cast to bf16, [N][K] layout)
    transcast<<<dim3(128 / 32, CDIM / 32), 256, 0, stream>>>(query_w, qw_bf, 128, CDIM);
    transcast<<<dim3(256 / 32, CDIM / 32), 256, 0, stream>>>(se1_w, se1w_bf, 256, CDIM);
    transcast<<<dim3(CDIM / 32, 256 / 32), 256, 0, stream>>>(se2_w, se2w_bf, CDIM, 256);
    transcast<<<dim3(CDIM / 32, CDIM / 32), 256, 0, stream>>>(out_w, outw_bf, CDIM, CDIM);

    // Wave projection (exact fp32) + stats
    wave_kernel<<<NTOK / 8, 256, 0, stream>>>(x, wave_w, wave_b, freq, decay, favg, pavg);

    // Query projection: silu(x @ query_w + b) -> q (f32)
    mfma_gemm<0, false><<<dim3(NTOK / 128, 128 / 128), 256, 0, stream>>>(
        x, qw_bf, query_b, nullptr, q, NTOK, 128, CDIM);

    // Adaptive conv -> conv (f32)
    adaptconv_kernel<<<NTOK, 256, 0, stream>>>(x, key_w, q, freq, decay, favg, pavg, conv);

    // SE1: silu(conv @ se1_w + b) -> tmp1 (bf16)
    mfma_gemm<1, false><<<dim3(NTOK / 128, 256 / 128), 256, 0, stream>>>(
        conv, se1w_bf, se1_b, nullptr, tmp1_bf, NTOK, 256, CDIM);

    // SE2: sigmoid(tmp1 @ se2_w + b) * conv -> g (bf16)
    mfma_gemm<2, true><<<dim3(NTOK / 128, CDIM / 128), 256, 0, stream>>>(
        tmp1_bf, se2w_bf, se2_b, conv, g_bf, NTOK, CDIM, 256);

    // OUT: silu(g @ out_w) -> d_out (f32)
    mfma_gemm<3, true><<<dim3(NTOK / 128, CDIM / 128), 256, 0, stream>>>(
        g_bf, outw_bf, nullptr, nullptr, d_out, NTOK, CDIM, CDIM);
}

// Round 3
// 210.452 us; speedup vs baseline: 5.1476x; 1.3385x over previous
//
#include <hip/hip_runtime.h>
#include <math.h>

#define HN 8
#define POSN 16
#define SN 33
#define HALF_SN 16
#define CDIM 1024
#define LDIM 4096
#define BDIM 2
#define NTOK (BDIM * LDIM)

typedef unsigned short u16;
typedef short short8 __attribute__((ext_vector_type(8)));
typedef u16 u16x8 __attribute__((ext_vector_type(8)));
typedef float f32x4 __attribute__((ext_vector_type(4)));

__device__ __forceinline__ float sigf(float x) { return 1.0f / (1.0f + expf(-x)); }
__device__ __forceinline__ float siluf(float x) { return x / (1.0f + expf(-x)); }
__device__ __forceinline__ u16 f2b(float f) {
    union { float f; unsigned u; } v; v.f = f;
    unsigned r = v.u + 0x7fffu + ((v.u >> 16) & 1u);   // RNE
    return (u16)(r >> 16);
}
__device__ __forceinline__ float b2f(u16 v) {
    union { unsigned u; float f; } x; x.u = ((unsigned)v) << 16; return x.f;
}
__device__ __forceinline__ void ld_lds16(const void* g, void* l) {
    __builtin_amdgcn_global_load_lds(
        (const __attribute__((address_space(1))) void*)g,
        (__attribute__((address_space(3))) void*)l, 16, 0, 0);
}

// ---------------------------------------------------------------------------
// x fp32 -> bf16 copy (gather source + QPROJ A operand).
// ---------------------------------------------------------------------------
__global__ __launch_bounds__(256) void xcast(
    const float* __restrict__ x, u16* __restrict__ xb)
{
    const int i = blockIdx.x * 256 + threadIdx.x;   // 8 elems per thread
    float4 a = ((const float4*)x)[(size_t)i * 2];
    float4 b = ((const float4*)x)[(size_t)i * 2 + 1];
    u16x8 o;
    o[0]=f2b(a.x); o[1]=f2b(a.y); o[2]=f2b(a.z); o[3]=f2b(a.w);
    o[4]=f2b(b.x); o[5]=f2b(b.y); o[6]=f2b(b.z); o[7]=f2b(b.w);
    ((u16x8*)xb)[i] = o;
}

// ---------------------------------------------------------------------------
// Weight prep: in[K][N] fp32 -> out[N][K] bf16 (transposed).
// ---------------------------------------------------------------------------
__global__ __launch_bounds__(256) void transcast(
    const float* __restrict__ in, u16* __restrict__ out, int N, int K)
{
    __shared__ float tile[32][33];
    const int bn = blockIdx.x * 32, bk = blockIdx.y * 32;
    const int tx = threadIdx.x & 31, ty = threadIdx.x >> 5;
    #pragma unroll
    for (int yy = ty; yy < 32; yy += 8)
        tile[yy][tx] = in[(size_t)(bk + yy) * N + bn + tx];
    __syncthreads();
    #pragma unroll
    for (int yy = ty; yy < 32; yy += 8)
        out[(size_t)(bn + yy) * K + bk + tx] = f2b(tile[tx][yy]);
}

// ---------------------------------------------------------------------------
// Wave projection (24 cols), exact fp32, FMA order bit-identical to round 2
// (protects the sample_idx int-trunc path). LDS-staged x rows + weight
// chunks; staging order doesn't change the serial k-ascending FMA chain.
// ---------------------------------------------------------------------------
__global__ __launch_bounds__(256) void wave_kernel(
    const float* __restrict__ x, const float* __restrict__ wave_w,
    const float* __restrict__ wave_b, float* __restrict__ freq,
    float* __restrict__ decay, float* __restrict__ favg, float* __restrict__ pavg)
{
    const int tid = threadIdx.x;
    const int tok = tid >> 5, col = tid & 31;
    const int t0 = blockIdx.x * 8;
    const int t = t0 + tok;
    __shared__ float xs[8][1024];
    __shared__ float wsc[256 * 24];
    __shared__ float wsh[8][24];
    __shared__ float fsh[8][8], psh[8][8];

    for (int i = tid; i < 2048; i += 256) {
        const int r = i >> 8, c4 = (i & 255) * 4;
        *(float4*)&xs[r][c4] = *(const float4*)(x + (size_t)(t0 + r) * CDIM + c4);
    }
    float acc = (col < 24) ? wave_b[col] : 0.0f;
    for (int k0 = 0; k0 < CDIM; k0 += 256) {
        __syncthreads();
        for (int i = tid; i < 1536; i += 256)
            *(float4*)&wsc[i * 4] = *(const float4*)(wave_w + (size_t)k0 * 24 + i * 4);
        __syncthreads();
        if (col < 24) {
            #pragma unroll 8
            for (int kk = 0; kk < 256; ++kk)
                acc += xs[tok][k0 + kk] * wsc[kk * 24 + col];
        }
    }
    if (col < 24) wsh[tok][col] = siluf(acc);
    __syncthreads();
    if (col < 8) {
        float f = sigf(wsh[tok][col])      * 15.0f + 1.0f;
        float p = tanhf(wsh[tok][8 + col]) * 16.0f;
        float d = sigf(wsh[tok][16 + col]) * 9.5f + 0.5f;
        freq[(size_t)t * HN + col] = f;
        decay[(size_t)t * HN + col] = d;
        fsh[tok][col] = f; psh[tok][col] = p;
    }
    __syncthreads();
    if (col == 0) {
        float fa = 0.f, pa = 0.f;
        for (int h = 0; h < HN; ++h) { fa += fsh[tok][h]; pa += psh[tok][h]; }
        favg[t] = fa * 0.125f; pavg[t] = pa * 0.125f;
    }
}

// ---------------------------------------------------------------------------
// bf16 MFMA GEMM, m97 structure: global_load_lds width-16, linear LDS,
// BK=32. CFG 0: 128x128 tile (2x2 waves of 64x64, acc 4x4).
// CFG 1: 32x128 tile (1x4 waves of 32x32, acc 2x2) for skinny-M/N cases.
// A: [M][K] bf16. B: [N][K] bf16 (pre-transposed).
// MODE 0: silu(acc+bias)->f32   MODE 1: silu(acc+bias)->bf16
// MODE 2: sigmoid(acc+bias)*mul_bf16->bf16   MODE 3: silu(acc)->f32
// ---------------------------------------------------------------------------
template <int MODE, int CFG>
__global__ __launch_bounds__(256) void mfma_gemm(
    const u16* __restrict__ A, const u16* __restrict__ Bt,
    const float* __restrict__ bias, const u16* __restrict__ mulb,
    void* __restrict__ Cptr, int M, int N, int K)
{
    constexpr int BM  = (CFG == 0) ? 128 : 32;
    constexpr int MI  = (CFG == 0) ? 4 : 2;
    constexpr int NJ  = (CFG == 0) ? 4 : 2;
    constexpr int ACH = BM / 16;          // 1KB chunks in A tile (8 or 2)
    constexpr int NCH = ACH + 8;          // + 8 chunks of B tile

    __shared__ u16 lds[(BM + 128) * 32];

    const int tid = threadIdx.x;
    const int bm = blockIdx.x * BM, bn = blockIdx.y * 128;
    const int wid = tid >> 6, lane = tid & 63;
    const int wr = (CFG == 0) ? (wid >> 1) * 64 : 0;
    const int wc = (CFG == 0) ? (wid & 1) * 64 : wid * 32;
    const int fm = lane & 15;
    const int kg = (lane >> 4) * 8;
    const int lrow = lane >> 2;           // row within 16-row chunk
    const int lk   = (lane & 3) * 8;      // k element offset within row

    f32x4 acc[MI][NJ];
    #pragma unroll
    for (int i = 0; i < MI; ++i)
        #pragma unroll
        for (int j = 0; j < NJ; ++j) acc[i][j] = (f32x4){0.f, 0.f, 0.f, 0.f};

    for (int k0 = 0; k0 < K; k0 += 32) {
        #pragma unroll
        for (int c = wid; c < NCH; c += 4) {
            const u16* gsrc = (c < ACH)
                ? A  + (size_t)(bm + c * 16 + lrow) * K + k0 + lk
                : Bt + (size_t)(bn + (c - ACH) * 16 + lrow) * K + k0 + lk;
            ld_lds16(gsrc, &lds[c * 512 + lane * 8]);
        }
        __syncthreads();
        short8 a[MI], b[NJ];
        #pragma unroll
        for (int i = 0; i < MI; ++i)
            a[i] = *(const short8*)&lds[(wr + i * 16 + fm) * 32 + kg];
        #pragma unroll
        for (int j = 0; j < NJ; ++j)
            b[j] = *(const short8*)&lds[(BM + wc + j * 16 + fm) * 32 + kg];
        #pragma unroll
        for (int i = 0; i < MI; ++i)
            #pragma unroll
            for (int j = 0; j < NJ; ++j)
                acc[i][j] = __builtin_amdgcn_mfma_f32_16x16x32_bf16(a[i], b[j], acc[i][j], 0, 0, 0);
        __syncthreads();
    }

    // C/D layout: col = lane&15, row = (lane>>4)*4 + e
    float* Cf = (float*)Cptr;
    u16* Cb = (u16*)Cptr;
    #pragma unroll
    for (int i = 0; i < MI; ++i) {
        const int row0 = bm + wr + i * 16 + (lane >> 4) * 4;
        #pragma unroll
        for (int j = 0; j < NJ; ++j) {
            const int col = bn + wc + j * 16 + fm;
            const float vb = (MODE == 3) ? 0.0f : bias[col];
            #pragma unroll
            for (int e = 0; e < 4; ++e) {
                const int row = row0 + e;
                float v = acc[i][j][e];
                if (MODE == 0 || MODE == 1) v = siluf(v + vb);
                if (MODE == 2) v = sigf(v + vb) * b2f(mulb[(size_t)row * N + col]);
                if (MODE == 3) v = siluf(v);
                if (MODE == 0 || MODE == 3) Cf[(size_t)row * N + col] = v;
                else                        Cb[(size_t)row * N + col] = f2b(v);
            }
        }
    }
}

// ---------------------------------------------------------------------------
// Adaptive conv: 2 tokens per block (128 threads each), bf16 gather,
// XCD-chunked block swizzle so each XCD's token range L2-fits x_bf.
// ---------------------------------------------------------------------------
__global__ __launch_bounds__(256) void adaptconv_kernel(
    const u16* __restrict__ xbf, const float* __restrict__ key_w,
    const float* __restrict__ q, const float* __restrict__ freq,
    const float* __restrict__ decay, const float* __restrict__ favg,
    const float* __restrict__ pavg, u16* __restrict__ out)
{
    // nwg = 4096, divisible by 8: chunked bijective swizzle
    const int bid = blockIdx.x;
    const int swz = (bid & 7) * (NTOK / 16) + (bid >> 3);
    const int sub = threadIdx.x >> 7, lt = threadIdx.x & 127;
    const int t = swz * 2 + sub;
    const int b = t / LDIM, l = t % LDIM;

    __shared__ float qs[2][128];
    __shared__ float kw[POSN];
    __shared__ float fr[2][HN], dc[2][HN];
    __shared__ int   idxs[2][SN];
    __shared__ float msk[2][SN];
    __shared__ float wgt[2][HN][SN];

    qs[sub][lt] = q[(size_t)t * 128 + lt];
    if (threadIdx.x < POSN) kw[threadIdx.x] = key_w[threadIdx.x];
    if (lt < HN) {
        fr[sub][lt] = freq[(size_t)t * HN + lt];
        dc[sub][lt] = decay[(size_t)t * HN + lt];
    }
    if (lt < SN) {
        float fa = favg[t], pa = pavg[t];
        float sp = (float)l + (float)(lt - HALF_SN) * fa + pa;
        bool v = (sp >= 0.0f) && (sp < (float)LDIM);
        int si = (int)sp;
        si = min(max(si, 0), LDIM - 1);
        idxs[sub][lt] = si;
        msk[sub][lt] = v ? 1.0f : 0.0f;
    }
    __syncthreads();

    for (int task = lt; task < HN * SN; task += 128) {
        const int h = task / SN, s = task % SN;
        float rel = fabsf((float)(s - HALF_SN)) * fr[sub][h];
        float acc = 0.0f;
        #pragma unroll
        for (int p = 0; p < POSN; ++p) acc += qs[sub][h * POSN + p] * siluf(rel * kw[p]);
        float lg = 0.25f * acc;
        if (msk[sub][s] == 0.0f) lg = -1e30f;
        wgt[sub][h][s] = lg;
    }
    __syncthreads();

    if (lt < HN) {
        const int h = lt;
        float m = -3.4e38f;
        for (int s = 0; s < SN; ++s) m = fmaxf(m, wgt[sub][h][s]);
        float pexp[SN];
        float ssum = 0.0f;
        for (int s = 0; s < SN; ++s) { float e = expf(wgt[sub][h][s] - m); pexp[s] = e; ssum += e; }
        float dci = fmaxf(dc[sub][h], 0.1f);
        float wsum = 0.0f;
        for (int s = 0; s < SN; ++s) {
            float rel = fabsf((float)(s - HALF_SN)) * fr[sub][h];
            float wv = (pexp[s] / ssum) * expf(-rel / dci) * msk[sub][s];
            pexp[s] = wv; wsum += wv;
        }
        float inv = 1.0f / (wsum + 1e-8f);
        for (int s = 0; s < SN; ++s) wgt[sub][h][s] = pexp[s] * inv;
    }
    __syncthreads();

    const u16* xb = xbf + (size_t)b * LDIM * CDIM;
    const int c8 = lt * 8;
    const int h = lt >> 4;
    float a0=0,a1=0,a2=0,a3=0,a4=0,a5=0,a6=0,a7=0;
    for (int s = 0; s < SN; ++s) {
        const float w = wgt[sub][h][s];
        u16x8 v = *(const u16x8*)(xb + (size_t)idxs[sub][s] * CDIM + c8);
        a0 += w * b2f(v[0]); a1 += w * b2f(v[1]);
        a2 += w * b2f(v[2]); a3 += w * b2f(v[3]);
        a4 += w * b2f(v[4]); a5 += w * b2f(v[5]);
        a6 += w * b2f(v[6]); a7 += w * b2f(v[7]);
    }
    u16x8 o;
    o[0]=f2b(a0); o[1]=f2b(a1); o[2]=f2b(a2); o[3]=f2b(a3);
    o[4]=f2b(a4); o[5]=f2b(a5); o[6]=f2b(a6); o[7]=f2b(a7);
    *(u16x8*)(out + (size_t)t * CDIM + c8) = o;
}

// ---------------------------------------------------------------------------
extern "C" void kernel_launch(void* const* d_in, const int* in_sizes, int n_in,
                              void* d_out, int out_size, void* d_ws, size_t ws_size,
                              hipStream_t stream)
{
    const float* x       = (const float*)d_in[0];
    const float* wave_w  = (const float*)d_in[1];
    const float* wave_b  = (const float*)d_in[2];
    const float* query_w = (const float*)d_in[3];
    const float* query_b = (const float*)d_in[4];
    const float* key_w   = (const float*)d_in[5];
    const float* out_w   = (const float*)d_in[6];
    const float* se1_w   = (const float*)d_in[7];
    const float* se1_b   = (const float*)d_in[8];
    const float* se2_w   = (const float*)d_in[9];
    const float* se2_b   = (const float*)d_in[10];

    char* wsb = (char*)d_ws;
    float* q     = (float*)wsb;         wsb += (size_t)NTOK * 128 * 4;
    float* freq  = (float*)wsb;         wsb += (size_t)NTOK * HN * 4;
    float* decay = (float*)wsb;         wsb += (size_t)NTOK * HN * 4;
    float* favg  = (float*)wsb;         wsb += (size_t)NTOK * 4;
    float* pavg  = (float*)wsb;         wsb += (size_t)NTOK * 4;
    u16* x_bf    = (u16*)wsb;           wsb += (size_t)NTOK * CDIM * 2;
    u16* conv_bf = (u16*)wsb;           wsb += (size_t)NTOK * CDIM * 2;
    u16* tmp1_bf = (u16*)wsb;           wsb += (size_t)NTOK * 256 * 2;
    u16* g_bf    = (u16*)wsb;           wsb += (size_t)NTOK * CDIM * 2;
    u16* qw_bf   = (u16*)wsb;           wsb += (size_t)128 * CDIM * 2;
    u16* se1w_bf = (u16*)wsb;           wsb += (size_t)256 * CDIM * 2;
    u16* se2w_bf = (u16*)wsb;           wsb += (size_t)CDIM * 256 * 2;
    u16* outw_bf = (u16*)wsb;           wsb += (size_t)CDIM * CDIM * 2;

    xcast<<<NTOK * CDIM / 8 / 256, 256, 0, stream>>>(x, x_bf);
    transcast<<<dim3(128 / 32, CDIM / 32), 256, 0, stream>>>(query_w, qw_bf, 128, CDIM);
    transcast<<<dim3(256 / 32, CDIM / 32), 256, 0, stream>>>(se1_w, se1w_bf, 256, CDIM);
    transcast<<<dim3(CDIM / 32, 256 / 32), 256, 0, stream>>>(se2_w, se2w_bf, CDIM, 256);
    transcast<<<dim3(CDIM / 32, CDIM / 32), 256, 0, stream>>>(out_w, outw_bf, CDIM, CDIM);

    // Wave projection (exact fp32, bit-identical order) + stats
    wave_kernel<<<NTOK / 8, 256, 0, stream>>>(x, wave_w, wave_b, freq, decay, favg, pavg);

    // QPROJ: silu(x @ query_w + b) -> q (f32).  M=8192, N=128, K=1024
    mfma_gemm<0, 1><<<dim3(NTOK / 32, 1), 256, 0, stream>>>(
        x_bf, qw_bf, query_b, nullptr, q, NTOK, 128, CDIM);

    // Adaptive conv -> conv (bf16)
    adaptconv_kernel<<<NTOK / 2, 256, 0, stream>>>(
        x_bf, key_w, q, freq, decay, favg, pavg, conv_bf);

    // SE1: silu(conv @ se1_w + b) -> tmp1 (bf16).  N=256, K=1024
    mfma_gemm<1, 1><<<dim3(NTOK / 32, 256 / 128), 256, 0, stream>>>(
        conv_bf, se1w_bf, se1_b, nullptr, tmp1_bf, NTOK, 256, CDIM);

    // SE2: sigmoid(tmp1 @ se2_w + b) * conv -> g (bf16).  N=1024, K=256
    mfma_gemm<2, 0><<<dim3(NTOK / 128, CDIM / 128), 256, 0, stream>>>(
        tmp1_bf, se2w_bf, se2_b, conv_bf, g_bf, NTOK, CDIM, 256);

    // OUT: silu(g @ out_w) -> d_out (f32).  N=1024, K=1024
    mfma_gemm<3, 0><<<dim3(NTOK / 128, CDIM / 128), 256, 0, stream>>>(
        g_bf, outw_bf, nullptr, nullptr, d_out, NTOK, CDIM, CDIM);
}

// Round 4
// 188.251 us; speedup vs baseline: 5.7546x; 1.1179x over previous
//
#include <hip/hip_runtime.h>
#include <math.h>

#define HN 8
#define POSN 16
#define SN 33
#define HALF_SN 16
#define CDIM 1024
#define LDIM 4096
#define BDIM 2
#define NTOK (BDIM * LDIM)

typedef unsigned short u16;
typedef short short8 __attribute__((ext_vector_type(8)));
typedef u16 u16x8 __attribute__((ext_vector_type(8)));
typedef unsigned int u32x4 __attribute__((ext_vector_type(4)));
typedef float f32x4 __attribute__((ext_vector_type(4)));

__device__ __forceinline__ float sigf(float x) { return 1.0f / (1.0f + expf(-x)); }
__device__ __forceinline__ float siluf(float x) { return x / (1.0f + expf(-x)); }
__device__ __forceinline__ u16 f2b(float f) {
    union { float f; unsigned u; } v; v.f = f;
    unsigned r = v.u + 0x7fffu + ((v.u >> 16) & 1u);   // RNE
    return (u16)(r >> 16);
}
__device__ __forceinline__ float b2f(u16 v) {
    union { unsigned u; float f; } x; x.u = ((unsigned)v) << 16; return x.f;
}
__device__ __forceinline__ float u2f(unsigned u) {
    union { unsigned u; float f; } x; x.u = u; return x.f;
}
__device__ __forceinline__ void ld_lds16(const void* g, void* l) {
    __builtin_amdgcn_global_load_lds(
        (const __attribute__((address_space(1))) void*)g,
        (__attribute__((address_space(3))) void*)l, 16, 0, 0);
}

// ---------------------------------------------------------------------------
// x fp32 -> bf16 copy (gather source + QPROJ A operand).
// ---------------------------------------------------------------------------
__global__ __launch_bounds__(256) void xcast(
    const float* __restrict__ x, u16* __restrict__ xb)
{
    const int i = blockIdx.x * 256 + threadIdx.x;   // 8 elems per thread
    float4 a = ((const float4*)x)[(size_t)i * 2];
    float4 b = ((const float4*)x)[(size_t)i * 2 + 1];
    u16x8 o;
    o[0]=f2b(a.x); o[1]=f2b(a.y); o[2]=f2b(a.z); o[3]=f2b(a.w);
    o[4]=f2b(b.x); o[5]=f2b(b.y); o[6]=f2b(b.z); o[7]=f2b(b.w);
    ((u16x8*)xb)[i] = o;
}

// ---------------------------------------------------------------------------
// Weight prep: in[K][N] fp32 -> out[N][K] bf16 (transposed).
// ---------------------------------------------------------------------------
__global__ __launch_bounds__(256) void transcast(
    const float* __restrict__ in, u16* __restrict__ out, int N, int K)
{
    __shared__ float tile[32][33];
    const int bn = blockIdx.x * 32, bk = blockIdx.y * 32;
    const int tx = threadIdx.x & 31, ty = threadIdx.x >> 5;
    #pragma unroll
    for (int yy = ty; yy < 32; yy += 8)
        tile[yy][tx] = in[(size_t)(bk + yy) * N + bn + tx];
    __syncthreads();
    #pragma unroll
    for (int yy = ty; yy < 32; yy += 8)
        out[(size_t)(bn + yy) * K + bk + tx] = f2b(tile[tx][yy]);
}

// ---------------------------------------------------------------------------
// Wave projection (24 cols), exact fp32, FMA order bit-identical to round 2/3
// (protects the sample_idx int-trunc path).
// ---------------------------------------------------------------------------
__global__ __launch_bounds__(256) void wave_kernel(
    const float* __restrict__ x, const float* __restrict__ wave_w,
    const float* __restrict__ wave_b, float* __restrict__ freq,
    float* __restrict__ decay, float* __restrict__ favg, float* __restrict__ pavg)
{
    const int tid = threadIdx.x;
    const int tok = tid >> 5, col = tid & 31;
    const int t0 = blockIdx.x * 8;
    const int t = t0 + tok;
    __shared__ float xs[8][1024];
    __shared__ float wsc[256 * 24];
    __shared__ float wsh[8][24];
    __shared__ float fsh[8][8], psh[8][8];

    for (int i = tid; i < 2048; i += 256) {
        const int r = i >> 8, c4 = (i & 255) * 4;
        *(float4*)&xs[r][c4] = *(const float4*)(x + (size_t)(t0 + r) * CDIM + c4);
    }
    float acc = (col < 24) ? wave_b[col] : 0.0f;
    for (int k0 = 0; k0 < CDIM; k0 += 256) {
        __syncthreads();
        for (int i = tid; i < 1536; i += 256)
            *(float4*)&wsc[i * 4] = *(const float4*)(wave_w + (size_t)k0 * 24 + i * 4);
        __syncthreads();
        if (col < 24) {
            #pragma unroll 8
            for (int kk = 0; kk < 256; ++kk)
                acc += xs[tok][k0 + kk] * wsc[kk * 24 + col];
        }
    }
    if (col < 24) wsh[tok][col] = siluf(acc);
    __syncthreads();
    if (col < 8) {
        float f = sigf(wsh[tok][col])      * 15.0f + 1.0f;
        float p = tanhf(wsh[tok][8 + col]) * 16.0f;
        float d = sigf(wsh[tok][16 + col]) * 9.5f + 0.5f;
        freq[(size_t)t * HN + col] = f;
        decay[(size_t)t * HN + col] = d;
        fsh[tok][col] = f; psh[tok][col] = p;
    }
    __syncthreads();
    if (col == 0) {
        float fa = 0.f, pa = 0.f;
        for (int h = 0; h < HN; ++h) { fa += fsh[tok][h]; pa += psh[tok][h]; }
        favg[t] = fa * 0.125f; pavg[t] = pa * 0.125f;
    }
}

// ---------------------------------------------------------------------------
// bf16 MFMA GEMM, m97 structure (unchanged from round 3).
// ---------------------------------------------------------------------------
template <int MODE, int CFG>
__global__ __launch_bounds__(256) void mfma_gemm(
    const u16* __restrict__ A, const u16* __restrict__ Bt,
    const float* __restrict__ bias, const u16* __restrict__ mulb,
    void* __restrict__ Cptr, int M, int N, int K)
{
    constexpr int BM  = (CFG == 0) ? 128 : 32;
    constexpr int MI  = (CFG == 0) ? 4 : 2;
    constexpr int NJ  = (CFG == 0) ? 4 : 2;
    constexpr int ACH = BM / 16;
    constexpr int NCH = ACH + 8;

    __shared__ u16 lds[(BM + 128) * 32];

    const int tid = threadIdx.x;
    const int bm = blockIdx.x * BM, bn = blockIdx.y * 128;
    const int wid = tid >> 6, lane = tid & 63;
    const int wr = (CFG == 0) ? (wid >> 1) * 64 : 0;
    const int wc = (CFG == 0) ? (wid & 1) * 64 : wid * 32;
    const int fm = lane & 15;
    const int kg = (lane >> 4) * 8;
    const int lrow = lane >> 2;
    const int lk   = (lane & 3) * 8;

    f32x4 acc[MI][NJ];
    #pragma unroll
    for (int i = 0; i < MI; ++i)
        #pragma unroll
        for (int j = 0; j < NJ; ++j) acc[i][j] = (f32x4){0.f, 0.f, 0.f, 0.f};

    for (int k0 = 0; k0 < K; k0 += 32) {
        #pragma unroll
        for (int c = wid; c < NCH; c += 4) {
            const u16* gsrc = (c < ACH)
                ? A  + (size_t)(bm + c * 16 + lrow) * K + k0 + lk
                : Bt + (size_t)(bn + (c - ACH) * 16 + lrow) * K + k0 + lk;
            ld_lds16(gsrc, &lds[c * 512 + lane * 8]);
        }
        __syncthreads();
        short8 a[MI], b[NJ];
        #pragma unroll
        for (int i = 0; i < MI; ++i)
            a[i] = *(const short8*)&lds[(wr + i * 16 + fm) * 32 + kg];
        #pragma unroll
        for (int j = 0; j < NJ; ++j)
            b[j] = *(const short8*)&lds[(BM + wc + j * 16 + fm) * 32 + kg];
        #pragma unroll
        for (int i = 0; i < MI; ++i)
            #pragma unroll
            for (int j = 0; j < NJ; ++j)
                acc[i][j] = __builtin_amdgcn_mfma_f32_16x16x32_bf16(a[i], b[j], acc[i][j], 0, 0, 0);
        __syncthreads();
    }

    float* Cf = (float*)Cptr;
    u16* Cb = (u16*)Cptr;
    #pragma unroll
    for (int i = 0; i < MI; ++i) {
        const int row0 = bm + wr + i * 16 + (lane >> 4) * 4;
        #pragma unroll
        for (int j = 0; j < NJ; ++j) {
            const int col = bn + wc + j * 16 + fm;
            const float vb = (MODE == 3) ? 0.0f : bias[col];
            #pragma unroll
            for (int e = 0; e < 4; ++e) {
                const int row = row0 + e;
                float v = acc[i][j][e];
                if (MODE == 0 || MODE == 1) v = siluf(v + vb);
                if (MODE == 2) v = sigf(v + vb) * b2f(mulb[(size_t)row * N + col]);
                if (MODE == 3) v = siluf(v);
                if (MODE == 0 || MODE == 3) Cf[(size_t)row * N + col] = v;
                else                        Cb[(size_t)row * N + col] = f2b(v);
            }
        }
    }
}

// ---------------------------------------------------------------------------
// Adaptive conv v2: symmetry-halved logits, wave-parallel softmax
// (16-lane group per head), byte-offset gather with 4-deep load chunks.
// ---------------------------------------------------------------------------
__global__ __launch_bounds__(256) void adaptconv_kernel(
    const u16* __restrict__ xbf, const float* __restrict__ key_w,
    const float* __restrict__ q, const float* __restrict__ freq,
    const float* __restrict__ decay, const float* __restrict__ favg,
    const float* __restrict__ pavg, u16* __restrict__ out)
{
    const int bid = blockIdx.x;
    const int swz = (bid & 7) * (NTOK / 16) + (bid >> 3);   // XCD-chunked
    const int sub = threadIdx.x >> 7, lt = threadIdx.x & 127;
    const int t = swz * 2 + sub;
    const int b = t / LDIM, l = t % LDIM;
    const int h = lt >> 4;        // head = 16-lane group
    const int li = lt & 15;       // lane in group

    __shared__ float qs[2][HN][17];     // padded: bank-conflict-free broadcast
    __shared__ float kw[POSN];
    __shared__ float fr[2][HN], dc[2][HN];
    __shared__ int   boff[2][SN];
    __shared__ float msk[2][SN];
    __shared__ float vsh[2][HN][17];    // logit magnitude by ds=|s-16|
    __shared__ float esh[2][HN][17];    // env by ds
    __shared__ float wgt[2][HN][SN];

    qs[sub][lt >> 4][lt & 15] = q[(size_t)t * 128 + lt];
    if (threadIdx.x < POSN) kw[threadIdx.x] = key_w[threadIdx.x];
    if (lt < HN) {
        fr[sub][lt] = freq[(size_t)t * HN + lt];
        dc[sub][lt] = decay[(size_t)t * HN + lt];
    }
    if (lt < SN) {
        float fa = favg[t], pa = pavg[t];
        float sp = (float)l + (float)(lt - HALF_SN) * fa + pa;
        bool v = (sp >= 0.0f) && (sp < (float)LDIM);
        int si = (int)sp;
        si = min(max(si, 0), LDIM - 1);
        boff[sub][lt] = si * (CDIM * 2);
        msk[sub][lt] = v ? 1.0f : 0.0f;
    }
    __syncthreads();

    // ---- logit magnitudes + env per distinct ds (17 values per head) ----
    {
        const float fh = fr[sub][h];
        const float dci = fmaxf(dc[sub][h], 0.1f);
        for (int ds = li; ds < 17; ds += 16) {
            float rel = (float)ds * fh;
            float acc = 0.0f;
            #pragma unroll
            for (int p = 0; p < POSN; ++p)
                acc += qs[sub][h][p] * siluf(rel * kw[p]);
            vsh[sub][h][ds] = 0.25f * acc;
            esh[sub][h][ds] = expf(-rel / dci);
        }
    }
    __syncthreads();

    // ---- wave-parallel masked softmax: lane li owns s = li, li+16, (li==0: 32)
    {
        const int ns = (li == 0) ? 3 : 2;
        int   sI[3] = { li, li + 16, 32 };
        float lg[3];
        #pragma unroll
        for (int k = 0; k < 3; ++k) {
            if (k < ns) {
                const int s = sI[k], ds = abs(s - 16);
                lg[k] = (msk[sub][s] != 0.0f) ? vsh[sub][h][ds] : -1e30f;
            } else lg[k] = -3.4e38f;
        }
        float m = fmaxf(lg[0], fmaxf(lg[1], lg[2]));
        #pragma unroll
        for (int d = 1; d < 16; d <<= 1) m = fmaxf(m, __shfl_xor(m, d));

        float e[3]; float ssum = 0.0f;
        #pragma unroll
        for (int k = 0; k < 3; ++k) {
            e[k] = (k < ns) ? expf(lg[k] - m) : 0.0f;
            ssum += e[k];
        }
        #pragma unroll
        for (int d = 1; d < 16; d <<= 1) ssum += __shfl_xor(ssum, d);

        float wv[3]; float wsum = 0.0f;
        #pragma unroll
        for (int k = 0; k < 3; ++k) {
            if (k < ns) {
                const int s = sI[k], ds = abs(s - 16);
                wv[k] = (e[k] / ssum) * esh[sub][h][ds] * msk[sub][s];
            } else wv[k] = 0.0f;
            wsum += wv[k];
        }
        #pragma unroll
        for (int d = 1; d < 16; d <<= 1) wsum += __shfl_xor(wsum, d);

        const float inv = 1.0f / (wsum + 1e-8f);
        #pragma unroll
        for (int k = 0; k < 3; ++k)
            if (k < ns) wgt[sub][h][sI[k]] = wv[k] * inv;
    }
    __syncthreads();

    // ---- gather: 8 channels per lane, 4 s-samples in flight ----
    const char* xbB = (const char*)(xbf + (size_t)b * LDIM * CDIM);
    const int cbyte = lt * 16;
    float a0=0,a1=0,a2=0,a3=0,a4=0,a5=0,a6=0,a7=0;

    #define GFMA(V, W) do { \
        a0 += (W) * u2f((V)[0] << 16); a1 += (W) * u2f((V)[0] & 0xffff0000u); \
        a2 += (W) * u2f((V)[1] << 16); a3 += (W) * u2f((V)[1] & 0xffff0000u); \
        a4 += (W) * u2f((V)[2] << 16); a5 += (W) * u2f((V)[2] & 0xffff0000u); \
        a6 += (W) * u2f((V)[3] << 16); a7 += (W) * u2f((V)[3] & 0xffff0000u); } while (0)

    int s = 0;
    for (; s + 4 <= SN; s += 4) {
        u32x4 v0 = *(const u32x4*)(xbB + boff[sub][s]     + cbyte);
        u32x4 v1 = *(const u32x4*)(xbB + boff[sub][s + 1] + cbyte);
        u32x4 v2 = *(const u32x4*)(xbB + boff[sub][s + 2] + cbyte);
        u32x4 v3 = *(const u32x4*)(xbB + boff[sub][s + 3] + cbyte);
        float w0 = wgt[sub][h][s],     w1 = wgt[sub][h][s + 1];
        float w2 = wgt[sub][h][s + 2], w3 = wgt[sub][h][s + 3];
        GFMA(v0, w0); GFMA(v1, w1); GFMA(v2, w2); GFMA(v3, w3);
    }
    for (; s < SN; ++s) {
        u32x4 v = *(const u32x4*)(xbB + boff[sub][s] + cbyte);
        float w = wgt[sub][h][s];
        GFMA(v, w);
    }
    #undef GFMA

    u16x8 o;
    o[0]=f2b(a0); o[1]=f2b(a1); o[2]=f2b(a2); o[3]=f2b(a3);
    o[4]=f2b(a4); o[5]=f2b(a5); o[6]=f2b(a6); o[7]=f2b(a7);
    *(u16x8*)(out + (size_t)t * CDIM + lt * 8) = o;
}

// ---------------------------------------------------------------------------
extern "C" void kernel_launch(void* const* d_in, const int* in_sizes, int n_in,
                              void* d_out, int out_size, void* d_ws, size_t ws_size,
                              hipStream_t stream)
{
    const float* x       = (const float*)d_in[0];
    const float* wave_w  = (const float*)d_in[1];
    const float* wave_b  = (const float*)d_in[2];
    const float* query_w = (const float*)d_in[3];
    const float* query_b = (const float*)d_in[4];
    const float* key_w   = (const float*)d_in[5];
    const float* out_w   = (const float*)d_in[6];
    const float* se1_w   = (const float*)d_in[7];
    const float* se1_b   = (const float*)d_in[8];
    const float* se2_w   = (const float*)d_in[9];
    const float* se2_b   = (const float*)d_in[10];

    char* wsb = (char*)d_ws;
    float* q     = (float*)wsb;         wsb += (size_t)NTOK * 128 * 4;
    float* freq  = (float*)wsb;         wsb += (size_t)NTOK * HN * 4;
    float* decay = (float*)wsb;         wsb += (size_t)NTOK * HN * 4;
    float* favg  = (float*)wsb;         wsb += (size_t)NTOK * 4;
    float* pavg  = (float*)wsb;         wsb += (size_t)NTOK * 4;
    u16* x_bf    = (u16*)wsb;           wsb += (size_t)NTOK * CDIM * 2;
    u16* conv_bf = (u16*)wsb;           wsb += (size_t)NTOK * CDIM * 2;
    u16* tmp1_bf = (u16*)wsb;           wsb += (size_t)NTOK * 256 * 2;
    u16* g_bf    = (u16*)wsb;           wsb += (size_t)NTOK * CDIM * 2;
    u16* qw_bf   = (u16*)wsb;           wsb += (size_t)128 * CDIM * 2;
    u16* se1w_bf = (u16*)wsb;           wsb += (size_t)256 * CDIM * 2;
    u16* se2w_bf = (u16*)wsb;           wsb += (size_t)CDIM * 256 * 2;
    u16* outw_bf = (u16*)wsb;           wsb += (size_t)CDIM * CDIM * 2;

    xcast<<<NTOK * CDIM / 8 / 256, 256, 0, stream>>>(x, x_bf);
    transcast<<<dim3(128 / 32, CDIM / 32), 256, 0, stream>>>(query_w, qw_bf, 128, CDIM);
    transcast<<<dim3(256 / 32, CDIM / 32), 256, 0, stream>>>(se1_w, se1w_bf, 256, CDIM);
    transcast<<<dim3(CDIM / 32, 256 / 32), 256, 0, stream>>>(se2_w, se2w_bf, CDIM, 256);
    transcast<<<dim3(CDIM / 32, CDIM / 32), 256, 0, stream>>>(out_w, outw_bf, CDIM, CDIM);

    wave_kernel<<<NTOK / 8, 256, 0, stream>>>(x, wave_w, wave_b, freq, decay, favg, pavg);

    // QPROJ: silu(x @ query_w + b) -> q (f32)
    mfma_gemm<0, 1><<<dim3(NTOK / 32, 1), 256, 0, stream>>>(
        x_bf, qw_bf, query_b, nullptr, q, NTOK, 128, CDIM);

    // Adaptive conv -> conv (bf16)
    adaptconv_kernel<<<NTOK / 2, 256, 0, stream>>>(
        x_bf, key_w, q, freq, decay, favg, pavg, conv_bf);

    // SE1: silu(conv @ se1_w + b) -> tmp1 (bf16)
    mfma_gemm<1, 1><<<dim3(NTOK / 32, 256 / 128), 256, 0, stream>>>(
        conv_bf, se1w_bf, se1_b, nullptr, tmp1_bf, NTOK, 256, CDIM);

    // SE2: sigmoid(tmp1 @ se2_w + b) * conv -> g (bf16)
    mfma_gemm<2, 0><<<dim3(NTOK / 128, CDIM / 128), 256, 0, stream>>>(
        tmp1_bf, se2w_bf, se2_b, conv_bf, g_bf, NTOK, CDIM, 256);

    // OUT: silu(g @ out_w) -> d_out (f32)
    mfma_gemm<3, 0><<<dim3(NTOK / 128, CDIM / 128), 256, 0, stream>>>(
        g_bf, outw_bf, nullptr, nullptr, d_out, NTOK, CDIM, CDIM);
}

// Round 5
// 155.957 us; speedup vs baseline: 6.9463x; 1.2071x over previous
//
#include <hip/hip_runtime.h>
#include <math.h>

#define HN 8
#define POSN 16
#define SN 33
#define HALF_SN 16
#define CDIM 1024
#define LDIM 4096
#define BDIM 2
#define NTOK (BDIM * LDIM)

typedef unsigned short u16;
typedef short short8 __attribute__((ext_vector_type(8)));
typedef u16 u16x8 __attribute__((ext_vector_type(8)));
typedef unsigned int u32x4 __attribute__((ext_vector_type(4)));
typedef float f32x4 __attribute__((ext_vector_type(4)));

// Precise versions (index-critical wave path ONLY)
__device__ __forceinline__ float sigf(float x) { return 1.0f / (1.0f + expf(-x)); }
__device__ __forceinline__ float siluf(float x) { return x / (1.0f + expf(-x)); }
// Fast versions (weight/epilogue paths: v_exp_f32 + v_rcp_f32)
__device__ __forceinline__ float frcp(float x) { return __builtin_amdgcn_rcpf(x); }
__device__ __forceinline__ float fexp(float x) { return __expf(x); }
__device__ __forceinline__ float fsig(float x) { return frcp(1.0f + fexp(-x)); }
__device__ __forceinline__ float fsilu(float x) { return x * fsig(x); }

__device__ __forceinline__ u16 f2b(float f) {
    union { float f; unsigned u; } v; v.f = f;
    unsigned r = v.u + 0x7fffu + ((v.u >> 16) & 1u);   // RNE
    return (u16)(r >> 16);
}
__device__ __forceinline__ float b2f(u16 v) {
    union { unsigned u; float f; } x; x.u = ((unsigned)v) << 16; return x.f;
}
__device__ __forceinline__ float u2f(unsigned u) {
    union { unsigned u; float f; } x; x.u = u; return x.f;
}
__device__ __forceinline__ void ld_lds16(const void* g, void* l) {
    __builtin_amdgcn_global_load_lds(
        (const __attribute__((address_space(1))) void*)g,
        (__attribute__((address_space(3))) void*)l, 16, 0, 0);
}

// ---------------------------------------------------------------------------
// x fp32 -> bf16 copy (gather source + QPROJ A operand).
// ---------------------------------------------------------------------------
__global__ __launch_bounds__(256) void xcast(
    const float* __restrict__ x, u16* __restrict__ xb)
{
    const int i = blockIdx.x * 256 + threadIdx.x;   // 8 elems per thread
    float4 a = ((const float4*)x)[(size_t)i * 2];
    float4 b = ((const float4*)x)[(size_t)i * 2 + 1];
    u16x8 o;
    o[0]=f2b(a.x); o[1]=f2b(a.y); o[2]=f2b(a.z); o[3]=f2b(a.w);
    o[4]=f2b(b.x); o[5]=f2b(b.y); o[6]=f2b(b.z); o[7]=f2b(b.w);
    ((u16x8*)xb)[i] = o;
}

// ---------------------------------------------------------------------------
// Weight prep: in[K][N] fp32 -> out[N][K] bf16 (transposed).
// ---------------------------------------------------------------------------
__global__ __launch_bounds__(256) void transcast(
    const float* __restrict__ in, u16* __restrict__ out, int N, int K)
{
    __shared__ float tile[32][33];
    const int bn = blockIdx.x * 32, bk = blockIdx.y * 32;
    const int tx = threadIdx.x & 31, ty = threadIdx.x >> 5;
    #pragma unroll
    for (int yy = ty; yy < 32; yy += 8)
        tile[yy][tx] = in[(size_t)(bk + yy) * N + bn + tx];
    __syncthreads();
    #pragma unroll
    for (int yy = ty; yy < 32; yy += 8)
        out[(size_t)(bn + yy) * K + bk + tx] = f2b(tile[tx][yy]);
}

// ---------------------------------------------------------------------------
// Wave projection (24 cols), exact fp32, FMA order bit-identical to rounds
// 2-4 (protects the sample_idx int-trunc path). x read direct from global
// (broadcast, zero reuse -> no LDS staging); weights transposed in LDS so
// the inner loop is vectorized: 1 global b128 + 1 ds_read_b128 per 4 FMAs.
// ---------------------------------------------------------------------------
__global__ __launch_bounds__(256) void wave_kernel(
    const float* __restrict__ x, const float* __restrict__ wave_w,
    const float* __restrict__ wave_b, float* __restrict__ freq,
    float* __restrict__ decay, float* __restrict__ favg, float* __restrict__ pavg)
{
    const int tid = threadIdx.x;
    const int tok = tid >> 5, col = tid & 31;
    const int t = blockIdx.x * 8 + tok;
    __shared__ float wsct[24][260];     // transposed weight chunk [col][k]
    __shared__ float wsh[8][24];
    __shared__ float fsh[8][8], psh[8][8];

    const float* xrow = x + (size_t)t * CDIM;
    float acc = (col < 24) ? wave_b[col] : 0.0f;

    for (int k0 = 0; k0 < CDIM; k0 += 256) {
        __syncthreads();
        {   // stage transposed: thread tid owns k-row k0+tid (24 floats)
            const float* wr = wave_w + (size_t)(k0 + tid) * 24;
            float4 w0 = *(const float4*)(wr + 0);
            float4 w1 = *(const float4*)(wr + 4);
            float4 w2 = *(const float4*)(wr + 8);
            float4 w3 = *(const float4*)(wr + 12);
            float4 w4 = *(const float4*)(wr + 16);
            float4 w5 = *(const float4*)(wr + 20);
            wsct[0][tid]=w0.x;  wsct[1][tid]=w0.y;  wsct[2][tid]=w0.z;  wsct[3][tid]=w0.w;
            wsct[4][tid]=w1.x;  wsct[5][tid]=w1.y;  wsct[6][tid]=w1.z;  wsct[7][tid]=w1.w;
            wsct[8][tid]=w2.x;  wsct[9][tid]=w2.y;  wsct[10][tid]=w2.z; wsct[11][tid]=w2.w;
            wsct[12][tid]=w3.x; wsct[13][tid]=w3.y; wsct[14][tid]=w3.z; wsct[15][tid]=w3.w;
            wsct[16][tid]=w4.x; wsct[17][tid]=w4.y; wsct[18][tid]=w4.z; wsct[19][tid]=w4.w;
            wsct[20][tid]=w5.x; wsct[21][tid]=w5.y; wsct[22][tid]=w5.z; wsct[23][tid]=w5.w;
        }
        __syncthreads();
        if (col < 24) {
            #pragma unroll 4
            for (int kk = 0; kk < 256; kk += 4) {
                float4 xv = *(const float4*)(xrow + k0 + kk);
                float4 wv = *(const float4*)(&wsct[col][kk]);
                acc += xv.x * wv.x; acc += xv.y * wv.y;
                acc += xv.z * wv.z; acc += xv.w * wv.w;
            }
        }
    }
    if (col < 24) wsh[tok][col] = siluf(acc);
    __syncthreads();
    if (col < 8) {
        float f = sigf(wsh[tok][col])      * 15.0f + 1.0f;
        float p = tanhf(wsh[tok][8 + col]) * 16.0f;
        float d = sigf(wsh[tok][16 + col]) * 9.5f + 0.5f;
        freq[(size_t)t * HN + col] = f;
        decay[(size_t)t * HN + col] = d;
        fsh[tok][col] = f; psh[tok][col] = p;
    }
    __syncthreads();
    if (col == 0) {
        float fa = 0.f, pa = 0.f;
        for (int h = 0; h < HN; ++h) { fa += fsh[tok][h]; pa += psh[tok][h]; }
        favg[t] = fa * 0.125f; pavg[t] = pa * 0.125f;
    }
}

// ---------------------------------------------------------------------------
// bf16 MFMA GEMM, m97 structure + T3-minimum 2-phase prefetch (dbuf LDS,
// stage next K-step before ds_read+MFMA of current, one barrier per step)
// + T1 XCD-chunked block swizzle (A-panel-sharing blocks on one XCD).
// ---------------------------------------------------------------------------
template <int MODE, int CFG>
__global__ __launch_bounds__(256) void mfma_gemm(
    const u16* __restrict__ A, const u16* __restrict__ Bt,
    const float* __restrict__ bias, const u16* __restrict__ mulb,
    void* __restrict__ Cptr, int M, int N, int K)
{
    constexpr int BM  = (CFG == 0) ? 128 : 32;
    constexpr int MI  = (CFG == 0) ? 4 : 2;
    constexpr int NJ  = (CFG == 0) ? 4 : 2;
    constexpr int ACH = BM / 16;
    constexpr int NCH = ACH + 8;

    __shared__ u16 lds[2][(BM + 128) * 32];

    // XCD-chunked swizzle: bx-major ordering, contiguous 1/8 chunks per XCD.
    const int nwg = gridDim.x * gridDim.y;
    const int flat = blockIdx.y * gridDim.x + blockIdx.x;
    const int swz = (flat & 7) * (nwg >> 3) + (flat >> 3);   // nwg % 8 == 0
    const int bxi = swz / gridDim.y, byi = swz % gridDim.y;

    const int tid = threadIdx.x;
    const int bm = bxi * BM, bn = byi * 128;
    const int wid = tid >> 6, lane = tid & 63;
    const int wr = (CFG == 0) ? (wid >> 1) * 64 : 0;
    const int wc = (CFG == 0) ? (wid & 1) * 64 : wid * 32;
    const int fm = lane & 15;
    const int kg = (lane >> 4) * 8;
    const int lrow = lane >> 2;
    const int lk   = (lane & 3) * 8;

    f32x4 acc[MI][NJ];
    #pragma unroll
    for (int i = 0; i < MI; ++i)
        #pragma unroll
        for (int j = 0; j < NJ; ++j) acc[i][j] = (f32x4){0.f, 0.f, 0.f, 0.f};

    auto stage = [&](u16* dst, int k0s) {
        #pragma unroll
        for (int c = wid; c < NCH; c += 4) {
            const u16* gsrc = (c < ACH)
                ? A  + (size_t)(bm + c * 16 + lrow) * K + k0s + lk
                : Bt + (size_t)(bn + (c - ACH) * 16 + lrow) * K + k0s + lk;
            ld_lds16(gsrc, dst + c * 512 + lane * 8);
        }
    };

    stage(&lds[0][0], 0);
    __syncthreads();                       // compiler drains vmcnt before barrier
    int cur = 0;
    for (int k0 = 0; k0 < K; k0 += 32) {
        const int k1 = (k0 + 32 < K) ? (k0 + 32) : k0;   // last iter: dummy
        stage(&lds[cur ^ 1][0], k1);       // prefetch next K-step (in flight)
        short8 a[MI], b[NJ];
        #pragma unroll
        for (int i = 0; i < MI; ++i)
            a[i] = *(const short8*)&lds[cur][(wr + i * 16 + fm) * 32 + kg];
        #pragma unroll
        for (int j = 0; j < NJ; ++j)
            b[j] = *(const short8*)&lds[cur][(BM + wc + j * 16 + fm) * 32 + kg];
        #pragma unroll
        for (int i = 0; i < MI; ++i)
            #pragma unroll
            for (int j = 0; j < NJ; ++j)
                acc[i][j] = __builtin_amdgcn_mfma_f32_16x16x32_bf16(a[i], b[j], acc[i][j], 0, 0, 0);
        __syncthreads();                   // one vmcnt(0)+barrier per K-step
        cur ^= 1;
    }

    float* Cf = (float*)Cptr;
    u16* Cb = (u16*)Cptr;
    #pragma unroll
    for (int i = 0; i < MI; ++i) {
        const int row0 = bm + wr + i * 16 + (lane >> 4) * 4;
        #pragma unroll
        for (int j = 0; j < NJ; ++j) {
            const int col = bn + wc + j * 16 + fm;
            const float vb = (MODE == 3) ? 0.0f : bias[col];
            #pragma unroll
            for (int e = 0; e < 4; ++e) {
                const int row = row0 + e;
                float v = acc[i][j][e];
                if (MODE == 0 || MODE == 1) v = fsilu(v + vb);
                if (MODE == 2) v = fsig(v + vb) * b2f(mulb[(size_t)row * N + col]);
                if (MODE == 3) v = fsilu(v);
                if (MODE == 0 || MODE == 3) Cf[(size_t)row * N + col] = v;
                else                        Cb[(size_t)row * N + col] = f2b(v);
            }
        }
    }
}

// ---------------------------------------------------------------------------
// Adaptive conv v3: symmetry-halved logits, wave-parallel softmax, fast
// transcendentals (v_exp/v_rcp — downstream of index computation only).
// ---------------------------------------------------------------------------
__global__ __launch_bounds__(256) void adaptconv_kernel(
    const u16* __restrict__ xbf, const float* __restrict__ key_w,
    const float* __restrict__ q, const float* __restrict__ freq,
    const float* __restrict__ decay, const float* __restrict__ favg,
    const float* __restrict__ pavg, u16* __restrict__ out)
{
    const int bid = blockIdx.x;
    const int swz = (bid & 7) * (NTOK / 16) + (bid >> 3);   // XCD-chunked
    const int sub = threadIdx.x >> 7, lt = threadIdx.x & 127;
    const int t = swz * 2 + sub;
    const int b = t / LDIM, l = t % LDIM;
    const int h = lt >> 4;        // head = 16-lane group
    const int li = lt & 15;       // lane in group

    __shared__ float qs[2][HN][17];
    __shared__ float kw[POSN];
    __shared__ float fr[2][HN], dc[2][HN];
    __shared__ int   boff[2][SN];
    __shared__ float msk[2][SN];
    __shared__ float vsh[2][HN][17];
    __shared__ float esh[2][HN][17];
    __shared__ float wgt[2][HN][SN];

    qs[sub][lt >> 4][lt & 15] = q[(size_t)t * 128 + lt];
    if (threadIdx.x < POSN) kw[threadIdx.x] = key_w[threadIdx.x];
    if (lt < HN) {
        fr[sub][lt] = freq[(size_t)t * HN + lt];
        dc[sub][lt] = decay[(size_t)t * HN + lt];
    }
    if (lt < SN) {
        // ---- index path: IDENTICAL expressions to rounds 2-4 ----
        float fa = favg[t], pa = pavg[t];
        float sp = (float)l + (float)(lt - HALF_SN) * fa + pa;
        bool v = (sp >= 0.0f) && (sp < (float)LDIM);
        int si = (int)sp;
        si = min(max(si, 0), LDIM - 1);
        boff[sub][lt] = si * (CDIM * 2);
        msk[sub][lt] = v ? 1.0f : 0.0f;
    }
    __syncthreads();

    // ---- logit magnitudes + env per distinct ds (17 per head) ----
    {
        const float fh = fr[sub][h];
        const float rdci = frcp(fmaxf(dc[sub][h], 0.1f));
        for (int ds = li; ds < 17; ds += 16) {
            float rel = (float)ds * fh;
            float acc = 0.0f;
            #pragma unroll
            for (int p = 0; p < POSN; ++p)
                acc += qs[sub][h][p] * fsilu(rel * kw[p]);
            vsh[sub][h][ds] = 0.25f * acc;
            esh[sub][h][ds] = fexp(-rel * rdci);
        }
    }
    __syncthreads();

    // ---- wave-parallel masked softmax ----
    {
        const int ns = (li == 0) ? 3 : 2;
        int   sI[3] = { li, li + 16, 32 };
        float lg[3];
        #pragma unroll
        for (int k = 0; k < 3; ++k) {
            if (k < ns) {
                const int s = sI[k], ds = abs(s - 16);
                lg[k] = (msk[sub][s] != 0.0f) ? vsh[sub][h][ds] : -1e30f;
            } else lg[k] = -3.4e38f;
        }
        float m = fmaxf(lg[0], fmaxf(lg[1], lg[2]));
        #pragma unroll
        for (int d = 1; d < 16; d <<= 1) m = fmaxf(m, __shfl_xor(m, d));

        float e[3]; float ssum = 0.0f;
        #pragma unroll
        for (int k = 0; k < 3; ++k) {
            e[k] = (k < ns) ? fexp(lg[k] - m) : 0.0f;
            ssum += e[k];
        }
        #pragma unroll
        for (int d = 1; d < 16; d <<= 1) ssum += __shfl_xor(ssum, d);

        const float rss = frcp(ssum);
        float wv[3]; float wsum = 0.0f;
        #pragma unroll
        for (int k = 0; k < 3; ++k) {
            if (k < ns) {
                const int s = sI[k], ds = abs(s - 16);
                wv[k] = e[k] * rss * esh[sub][h][ds] * msk[sub][s];
            } else wv[k] = 0.0f;
            wsum += wv[k];
        }
        #pragma unroll
        for (int d = 1; d < 16; d <<= 1) wsum += __shfl_xor(wsum, d);

        const float inv = frcp(wsum + 1e-8f);
        #pragma unroll
        for (int k = 0; k < 3; ++k)
            if (k < ns) wgt[sub][h][sI[k]] = wv[k] * inv;
    }
    __syncthreads();

    // ---- gather: 8 channels per lane, 4 samples in flight ----
    const char* xbB = (const char*)(xbf + (size_t)b * LDIM * CDIM);
    const int cbyte = lt * 16;
    float a0=0,a1=0,a2=0,a3=0,a4=0,a5=0,a6=0,a7=0;

    #define GFMA(V, W) do { \
        a0 += (W) * u2f((V)[0] << 16); a1 += (W) * u2f((V)[0] & 0xffff0000u); \
        a2 += (W) * u2f((V)[1] << 16); a3 += (W) * u2f((V)[1] & 0xffff0000u); \
        a4 += (W) * u2f((V)[2] << 16); a5 += (W) * u2f((V)[2] & 0xffff0000u); \
        a6 += (W) * u2f((V)[3] << 16); a7 += (W) * u2f((V)[3] & 0xffff0000u); } while (0)

    int s = 0;
    for (; s + 4 <= SN; s += 4) {
        u32x4 v0 = *(const u32x4*)(xbB + boff[sub][s]     + cbyte);
        u32x4 v1 = *(const u32x4*)(xbB + boff[sub][s + 1] + cbyte);
        u32x4 v2 = *(const u32x4*)(xbB + boff[sub][s + 2] + cbyte);
        u32x4 v3 = *(const u32x4*)(xbB + boff[sub][s + 3] + cbyte);
        float w0 = wgt[sub][h][s],     w1 = wgt[sub][h][s + 1];
        float w2 = wgt[sub][h][s + 2], w3 = wgt[sub][h][s + 3];
        GFMA(v0, w0); GFMA(v1, w1); GFMA(v2, w2); GFMA(v3, w3);
    }
    for (; s < SN; ++s) {
        u32x4 v = *(const u32x4*)(xbB + boff[sub][s] + cbyte);
        float w = wgt[sub][h][s];
        GFMA(v, w);
    }
    #undef GFMA

    u16x8 o;
    o[0]=f2b(a0); o[1]=f2b(a1); o[2]=f2b(a2); o[3]=f2b(a3);
    o[4]=f2b(a4); o[5]=f2b(a5); o[6]=f2b(a6); o[7]=f2b(a7);
    *(u16x8*)(out + (size_t)t * CDIM + lt * 8) = o;
}

// ---------------------------------------------------------------------------
extern "C" void kernel_launch(void* const* d_in, const int* in_sizes, int n_in,
                              void* d_out, int out_size, void* d_ws, size_t ws_size,
                              hipStream_t stream)
{
    const float* x       = (const float*)d_in[0];
    const float* wave_w  = (const float*)d_in[1];
    const float* wave_b  = (const float*)d_in[2];
    const float* query_w = (const float*)d_in[3];
    const float* query_b = (const float*)d_in[4];
    const float* key_w   = (const float*)d_in[5];
    const float* out_w   = (const float*)d_in[6];
    const float* se1_w   = (const float*)d_in[7];
    const float* se1_b   = (const float*)d_in[8];
    const float* se2_w   = (const float*)d_in[9];
    const float* se2_b   = (const float*)d_in[10];

    char* wsb = (char*)d_ws;
    float* q     = (float*)wsb;         wsb += (size_t)NTOK * 128 * 4;
    float* freq  = (float*)wsb;         wsb += (size_t)NTOK * HN * 4;
    float* decay = (float*)wsb;         wsb += (size_t)NTOK * HN * 4;
    float* favg  = (float*)wsb;         wsb += (size_t)NTOK * 4;
    float* pavg  = (float*)wsb;         wsb += (size_t)NTOK * 4;
    u16* x_bf    = (u16*)wsb;           wsb += (size_t)NTOK * CDIM * 2;
    u16* conv_bf = (u16*)wsb;           wsb += (size_t)NTOK * CDIM * 2;
    u16* tmp1_bf = (u16*)wsb;           wsb += (size_t)NTOK * 256 * 2;
    u16* g_bf    = (u16*)wsb;           wsb += (size_t)NTOK * CDIM * 2;
    u16* qw_bf   = (u16*)wsb;           wsb += (size_t)128 * CDIM * 2;
    u16* se1w_bf = (u16*)wsb;           wsb += (size_t)256 * CDIM * 2;
    u16* se2w_bf = (u16*)wsb;           wsb += (size_t)CDIM * 256 * 2;
    u16* outw_bf = (u16*)wsb;           wsb += (size_t)CDIM * CDIM * 2;

    xcast<<<NTOK * CDIM / 8 / 256, 256, 0, stream>>>(x, x_bf);
    transcast<<<dim3(128 / 32, CDIM / 32), 256, 0, stream>>>(query_w, qw_bf, 128, CDIM);
    transcast<<<dim3(256 / 32, CDIM / 32), 256, 0, stream>>>(se1_w, se1w_bf, 256, CDIM);
    transcast<<<dim3(CDIM / 32, 256 / 32), 256, 0, stream>>>(se2_w, se2w_bf, CDIM, 256);
    transcast<<<dim3(CDIM / 32, CDIM / 32), 256, 0, stream>>>(out_w, outw_bf, CDIM, CDIM);

    wave_kernel<<<NTOK / 8, 256, 0, stream>>>(x, wave_w, wave_b, freq, decay, favg, pavg);

    // QPROJ: silu(x @ query_w + b) -> q (f32)
    mfma_gemm<0, 1><<<dim3(NTOK / 32, 1), 256, 0, stream>>>(
        x_bf, qw_bf, query_b, nullptr, q, NTOK, 128, CDIM);

    // Adaptive conv -> conv (bf16)
    adaptconv_kernel<<<NTOK / 2, 256, 0, stream>>>(
        x_bf, key_w, q, freq, decay, favg, pavg, conv_bf);

    // SE1: silu(conv @ se1_w + b) -> tmp1 (bf16)
    mfma_gemm<1, 1><<<dim3(NTOK / 32, 256 / 128), 256, 0, stream>>>(
        conv_bf, se1w_bf, se1_b, nullptr, tmp1_bf, NTOK, 256, CDIM);

    // SE2: sigmoid(tmp1 @ se2_w + b) * conv -> g (bf16)
    mfma_gemm<2, 0><<<dim3(NTOK / 128, CDIM / 128), 256, 0, stream>>>(
        tmp1_bf, se2w_bf, se2_b, conv_bf, g_bf, NTOK, CDIM, 256);

    // OUT: silu(g @ out_w) -> d_out (f32)
    mfma_gemm<3, 0><<<dim3(NTOK / 128, CDIM / 128), 256, 0, stream>>>(
        g_bf, outw_bf, nullptr, nullptr, d_out, NTOK, CDIM, CDIM);
}

// Round 6
// 145.663 us; speedup vs baseline: 7.4371x; 1.0707x over previous
//
#include <hip/hip_runtime.h>
#include <math.h>

#define HN 8
#define POSN 16
#define SN 33
#define HALF_SN 16
#define CDIM 1024
#define LDIM 4096
#define BDIM 2
#define NTOK (BDIM * LDIM)

typedef unsigned short u16;
typedef short short8 __attribute__((ext_vector_type(8)));
typedef u16 u16x8 __attribute__((ext_vector_type(8)));
typedef unsigned int u32x4 __attribute__((ext_vector_type(4)));
typedef float f32x4 __attribute__((ext_vector_type(4)));

// Precise versions (index-critical wave path ONLY)
__device__ __forceinline__ float sigf(float x) { return 1.0f / (1.0f + expf(-x)); }
__device__ __forceinline__ float siluf(float x) { return x / (1.0f + expf(-x)); }
// Fast versions (weight/epilogue paths: v_exp_f32 + v_rcp_f32)
__device__ __forceinline__ float frcp(float x) { return __builtin_amdgcn_rcpf(x); }
__device__ __forceinline__ float fexp(float x) { return __expf(x); }
__device__ __forceinline__ float fsig(float x) { return frcp(1.0f + fexp(-x)); }
__device__ __forceinline__ float fsilu(float x) { return x * fsig(x); }

__device__ __forceinline__ u16 f2b(float f) {
    union { float f; unsigned u; } v; v.f = f;
    unsigned r = v.u + 0x7fffu + ((v.u >> 16) & 1u);   // RNE
    return (u16)(r >> 16);
}
__device__ __forceinline__ float b2f(u16 v) {
    union { unsigned u; float f; } x; x.u = ((unsigned)v) << 16; return x.f;
}
__device__ __forceinline__ float u2f(unsigned u) {
    union { unsigned u; float f; } x; x.u = u; return x.f;
}
__device__ __forceinline__ void ld_lds16(const void* g, void* l) {
    __builtin_amdgcn_global_load_lds(
        (const __attribute__((address_space(1))) void*)g,
        (__attribute__((address_space(3))) void*)l, 16, 0, 0);
}

// ---------------------------------------------------------------------------
// All 4 weight preps in ONE launch: in[K][N] fp32 -> out[N][K] bf16.
// Flat block-range dispatch:
//   [0,128)    query_w  N=128  K=1024   (4 x 32 tiles)
//   [128,384)  se1_w    N=256  K=1024   (8 x 32)
//   [384,640)  se2_w    N=1024 K=256    (32 x 8)
//   [640,1664) out_w    N=1024 K=1024   (32 x 32)
// ---------------------------------------------------------------------------
__global__ __launch_bounds__(256) void transcast_all(
    const float* __restrict__ qw, const float* __restrict__ s1,
    const float* __restrict__ s2, const float* __restrict__ ow,
    u16* __restrict__ oq, u16* __restrict__ o1,
    u16* __restrict__ o2, u16* __restrict__ oo)
{
    const int bid = blockIdx.x;
    const float* in; u16* out; int N, K, base;
    if      (bid < 128) { in = qw; out = oq; N = 128;  K = 1024; base = 0;   }
    else if (bid < 384) { in = s1; out = o1; N = 256;  K = 1024; base = 128; }
    else if (bid < 640) { in = s2; out = o2; N = 1024; K = 256;  base = 384; }
    else                { in = ow; out = oo; N = 1024; K = 1024; base = 640; }
    const int rel = bid - base, nx = N / 32;
    const int bn = (rel % nx) * 32, bk = (rel / nx) * 32;

    __shared__ float tile[32][33];
    const int tx = threadIdx.x & 31, ty = threadIdx.x >> 5;
    #pragma unroll
    for (int yy = ty; yy < 32; yy += 8)
        tile[yy][tx] = in[(size_t)(bk + yy) * N + bn + tx];
    __syncthreads();
    #pragma unroll
    for (int yy = ty; yy < 32; yy += 8)
        out[(size_t)(bn + yy) * K + bk + tx] = f2b(tile[tx][yy]);
}

// ---------------------------------------------------------------------------
// Wave projection (24 cols), exact fp32, FMA order bit-identical to rounds
// 2-5 (protects the sample_idx int-trunc path). NOW ALSO emits x_bf (fused
// xcast): cast loop runs first (warms L1/L2), never touches acc.
// ---------------------------------------------------------------------------
__global__ __launch_bounds__(256) void wave_kernel(
    const float* __restrict__ x, const float* __restrict__ wave_w,
    const float* __restrict__ wave_b, u16* __restrict__ xbf,
    float* __restrict__ freq, float* __restrict__ decay,
    float* __restrict__ favg, float* __restrict__ pavg)
{
    const int tid = threadIdx.x;
    const int tok = tid >> 5, col = tid & 31;
    const int t0 = blockIdx.x * 8;
    const int t = t0 + tok;
    __shared__ float wsct[24][260];     // transposed weight chunk [col][k]
    __shared__ float wsh[8][24];
    __shared__ float fsh[8][8], psh[8][8];

    // ---- fused xcast: 8 rows x 1024 ch -> bf16 (8 floats per iter) ----
    for (int i = tid; i < 1024; i += 256) {
        const int r = i >> 7, c8 = (i & 127) * 8;
        const float* src = x + (size_t)(t0 + r) * CDIM + c8;
        float4 a = *(const float4*)(src);
        float4 b = *(const float4*)(src + 4);
        u16x8 o;
        o[0]=f2b(a.x); o[1]=f2b(a.y); o[2]=f2b(a.z); o[3]=f2b(a.w);
        o[4]=f2b(b.x); o[5]=f2b(b.y); o[6]=f2b(b.z); o[7]=f2b(b.w);
        *(u16x8*)(xbf + (size_t)(t0 + r) * CDIM + c8) = o;
    }

    const float* xrow = x + (size_t)t * CDIM;
    float acc = (col < 24) ? wave_b[col] : 0.0f;

    for (int k0 = 0; k0 < CDIM; k0 += 256) {
        __syncthreads();
        {   // stage transposed: thread tid owns k-row k0+tid (24 floats)
            const float* wr = wave_w + (size_t)(k0 + tid) * 24;
            float4 w0 = *(const float4*)(wr + 0);
            float4 w1 = *(const float4*)(wr + 4);
            float4 w2 = *(const float4*)(wr + 8);
            float4 w3 = *(const float4*)(wr + 12);
            float4 w4 = *(const float4*)(wr + 16);
            float4 w5 = *(const float4*)(wr + 20);
            wsct[0][tid]=w0.x;  wsct[1][tid]=w0.y;  wsct[2][tid]=w0.z;  wsct[3][tid]=w0.w;
            wsct[4][tid]=w1.x;  wsct[5][tid]=w1.y;  wsct[6][tid]=w1.z;  wsct[7][tid]=w1.w;
            wsct[8][tid]=w2.x;  wsct[9][tid]=w2.y;  wsct[10][tid]=w2.z; wsct[11][tid]=w2.w;
            wsct[12][tid]=w3.x; wsct[13][tid]=w3.y; wsct[14][tid]=w3.z; wsct[15][tid]=w3.w;
            wsct[16][tid]=w4.x; wsct[17][tid]=w4.y; wsct[18][tid]=w4.z; wsct[19][tid]=w4.w;
            wsct[20][tid]=w5.x; wsct[21][tid]=w5.y; wsct[22][tid]=w5.z; wsct[23][tid]=w5.w;
        }
        __syncthreads();
        if (col < 24) {
            #pragma unroll 4
            for (int kk = 0; kk < 256; kk += 4) {
                float4 xv = *(const float4*)(xrow + k0 + kk);
                float4 wv = *(const float4*)(&wsct[col][kk]);
                acc += xv.x * wv.x; acc += xv.y * wv.y;
                acc += xv.z * wv.z; acc += xv.w * wv.w;
            }
        }
    }
    if (col < 24) wsh[tok][col] = siluf(acc);
    __syncthreads();
    if (col < 8) {
        float f = sigf(wsh[tok][col])      * 15.0f + 1.0f;
        float p = tanhf(wsh[tok][8 + col]) * 16.0f;
        float d = sigf(wsh[tok][16 + col]) * 9.5f + 0.5f;
        freq[(size_t)t * HN + col] = f;
        decay[(size_t)t * HN + col] = d;
        fsh[tok][col] = f; psh[tok][col] = p;
    }
    __syncthreads();
    if (col == 0) {
        float fa = 0.f, pa = 0.f;
        for (int h = 0; h < HN; ++h) { fa += fsh[tok][h]; pa += psh[tok][h]; }
        favg[t] = fa * 0.125f; pavg[t] = pa * 0.125f;
    }
}

// ---------------------------------------------------------------------------
// bf16 MFMA GEMM, m97 structure + T3-minimum 2-phase prefetch + T1 XCD
// swizzle (unchanged from round 5).
// MODE 1: silu(acc+bias)->bf16   MODE 2: sigmoid(acc+bias)*mul_bf16->bf16
// MODE 3: silu(acc)->f32
// ---------------------------------------------------------------------------
template <int MODE, int CFG>
__global__ __launch_bounds__(256) void mfma_gemm(
    const u16* __restrict__ A, const u16* __restrict__ Bt,
    const float* __restrict__ bias, const u16* __restrict__ mulb,
    void* __restrict__ Cptr, int M, int N, int K)
{
    constexpr int BM  = (CFG == 0) ? 128 : 32;
    constexpr int MI  = (CFG == 0) ? 4 : 2;
    constexpr int NJ  = (CFG == 0) ? 4 : 2;
    constexpr int ACH = BM / 16;
    constexpr int NCH = ACH + 8;

    __shared__ u16 lds[2][(BM + 128) * 32];

    const int nwg = gridDim.x * gridDim.y;
    const int flat = blockIdx.y * gridDim.x + blockIdx.x;
    const int swz = (flat & 7) * (nwg >> 3) + (flat >> 3);   // nwg % 8 == 0
    const int bxi = swz / gridDim.y, byi = swz % gridDim.y;

    const int tid = threadIdx.x;
    const int bm = bxi * BM, bn = byi * 128;
    const int wid = tid >> 6, lane = tid & 63;
    const int wr = (CFG == 0) ? (wid >> 1) * 64 : 0;
    const int wc = (CFG == 0) ? (wid & 1) * 64 : wid * 32;
    const int fm = lane & 15;
    const int kg = (lane >> 4) * 8;
    const int lrow = lane >> 2;
    const int lk   = (lane & 3) * 8;

    f32x4 acc[MI][NJ];
    #pragma unroll
    for (int i = 0; i < MI; ++i)
        #pragma unroll
        for (int j = 0; j < NJ; ++j) acc[i][j] = (f32x4){0.f, 0.f, 0.f, 0.f};

    auto stage = [&](u16* dst, int k0s) {
        #pragma unroll
        for (int c = wid; c < NCH; c += 4) {
            const u16* gsrc = (c < ACH)
                ? A  + (size_t)(bm + c * 16 + lrow) * K + k0s + lk
                : Bt + (size_t)(bn + (c - ACH) * 16 + lrow) * K + k0s + lk;
            ld_lds16(gsrc, dst + c * 512 + lane * 8);
        }
    };

    stage(&lds[0][0], 0);
    __syncthreads();
    int cur = 0;
    for (int k0 = 0; k0 < K; k0 += 32) {
        const int k1 = (k0 + 32 < K) ? (k0 + 32) : k0;
        stage(&lds[cur ^ 1][0], k1);       // prefetch next K-step (in flight)
        short8 a[MI], b[NJ];
        #pragma unroll
        for (int i = 0; i < MI; ++i)
            a[i] = *(const short8*)&lds[cur][(wr + i * 16 + fm) * 32 + kg];
        #pragma unroll
        for (int j = 0; j < NJ; ++j)
            b[j] = *(const short8*)&lds[cur][(BM + wc + j * 16 + fm) * 32 + kg];
        #pragma unroll
        for (int i = 0; i < MI; ++i)
            #pragma unroll
            for (int j = 0; j < NJ; ++j)
                acc[i][j] = __builtin_amdgcn_mfma_f32_16x16x32_bf16(a[i], b[j], acc[i][j], 0, 0, 0);
        __syncthreads();
        cur ^= 1;
    }

    float* Cf = (float*)Cptr;
    u16* Cb = (u16*)Cptr;
    #pragma unroll
    for (int i = 0; i < MI; ++i) {
        const int row0 = bm + wr + i * 16 + (lane >> 4) * 4;
        #pragma unroll
        for (int j = 0; j < NJ; ++j) {
            const int col = bn + wc + j * 16 + fm;
            const float vb = (MODE == 3) ? 0.0f : bias[col];
            #pragma unroll
            for (int e = 0; e < 4; ++e) {
                const int row = row0 + e;
                float v = acc[i][j][e];
                if (MODE == 1) v = fsilu(v + vb);
                if (MODE == 2) v = fsig(v + vb) * b2f(mulb[(size_t)row * N + col]);
                if (MODE == 3) v = fsilu(v);
                if (MODE == 3) Cf[(size_t)row * N + col] = v;
                else           Cb[(size_t)row * N + col] = f2b(v);
            }
        }
    }
}

// ---------------------------------------------------------------------------
// Adaptive conv (unchanged from round 5, except q is now bf16).
// ---------------------------------------------------------------------------
__global__ __launch_bounds__(256) void adaptconv_kernel(
    const u16* __restrict__ xbf, const float* __restrict__ key_w,
    const u16* __restrict__ qb, const float* __restrict__ freq,
    const float* __restrict__ decay, const float* __restrict__ favg,
    const float* __restrict__ pavg, u16* __restrict__ out)
{
    const int bid = blockIdx.x;
    const int swz = (bid & 7) * (NTOK / 16) + (bid >> 3);   // XCD-chunked
    const int sub = threadIdx.x >> 7, lt = threadIdx.x & 127;
    const int t = swz * 2 + sub;
    const int b = t / LDIM, l = t % LDIM;
    const int h = lt >> 4;
    const int li = lt & 15;

    __shared__ float qs[2][HN][17];
    __shared__ float kw[POSN];
    __shared__ float fr[2][HN], dc[2][HN];
    __shared__ int   boff[2][SN];
    __shared__ float msk[2][SN];
    __shared__ float vsh[2][HN][17];
    __shared__ float esh[2][HN][17];
    __shared__ float wgt[2][HN][SN];

    qs[sub][lt >> 4][lt & 15] = b2f(qb[(size_t)t * 128 + lt]);
    if (threadIdx.x < POSN) kw[threadIdx.x] = key_w[threadIdx.x];
    if (lt < HN) {
        fr[sub][lt] = freq[(size_t)t * HN + lt];
        dc[sub][lt] = decay[(size_t)t * HN + lt];
    }
    if (lt < SN) {
        // ---- index path: IDENTICAL expressions to rounds 2-5 ----
        float fa = favg[t], pa = pavg[t];
        float sp = (float)l + (float)(lt - HALF_SN) * fa + pa;
        bool v = (sp >= 0.0f) && (sp < (float)LDIM);
        int si = (int)sp;
        si = min(max(si, 0), LDIM - 1);
        boff[sub][lt] = si * (CDIM * 2);
        msk[sub][lt] = v ? 1.0f : 0.0f;
    }
    __syncthreads();

    {
        const float fh = fr[sub][h];
        const float rdci = frcp(fmaxf(dc[sub][h], 0.1f));
        for (int ds = li; ds < 17; ds += 16) {
            float rel = (float)ds * fh;
            float acc = 0.0f;
            #pragma unroll
            for (int p = 0; p < POSN; ++p)
                acc += qs[sub][h][p] * fsilu(rel * kw[p]);
            vsh[sub][h][ds] = 0.25f * acc;
            esh[sub][h][ds] = fexp(-rel * rdci);
        }
    }
    __syncthreads();

    {
        const int ns = (li == 0) ? 3 : 2;
        int   sI[3] = { li, li + 16, 32 };
        float lg[3];
        #pragma unroll
        for (int k = 0; k < 3; ++k) {
            if (k < ns) {
                const int s = sI[k], ds = abs(s - 16);
                lg[k] = (msk[sub][s] != 0.0f) ? vsh[sub][h][ds] : -1e30f;
            } else lg[k] = -3.4e38f;
        }
        float m = fmaxf(lg[0], fmaxf(lg[1], lg[2]));
        #pragma unroll
        for (int d = 1; d < 16; d <<= 1) m = fmaxf(m, __shfl_xor(m, d));

        float e[3]; float ssum = 0.0f;
        #pragma unroll
        for (int k = 0; k < 3; ++k) {
            e[k] = (k < ns) ? fexp(lg[k] - m) : 0.0f;
            ssum += e[k];
        }
        #pragma unroll
        for (int d = 1; d < 16; d <<= 1) ssum += __shfl_xor(ssum, d);

        const float rss = frcp(ssum);
        float wv[3]; float wsum = 0.0f;
        #pragma unroll
        for (int k = 0; k < 3; ++k) {
            if (k < ns) {
                const int s = sI[k], ds = abs(s - 16);
                wv[k] = e[k] * rss * esh[sub][h][ds] * msk[sub][s];
            } else wv[k] = 0.0f;
            wsum += wv[k];
        }
        #pragma unroll
        for (int d = 1; d < 16; d <<= 1) wsum += __shfl_xor(wsum, d);

        const float inv = frcp(wsum + 1e-8f);
        #pragma unroll
        for (int k = 0; k < 3; ++k)
            if (k < ns) wgt[sub][h][sI[k]] = wv[k] * inv;
    }
    __syncthreads();

    const char* xbB = (const char*)(xbf + (size_t)b * LDIM * CDIM);
    const int cbyte = lt * 16;
    float a0=0,a1=0,a2=0,a3=0,a4=0,a5=0,a6=0,a7=0;

    #define GFMA(V, W) do { \
        a0 += (W) * u2f((V)[0] << 16); a1 += (W) * u2f((V)[0] & 0xffff0000u); \
        a2 += (W) * u2f((V)[1] << 16); a3 += (W) * u2f((V)[1] & 0xffff0000u); \
        a4 += (W) * u2f((V)[2] << 16); a5 += (W) * u2f((V)[2] & 0xffff0000u); \
        a6 += (W) * u2f((V)[3] << 16); a7 += (W) * u2f((V)[3] & 0xffff0000u); } while (0)

    int s = 0;
    for (; s + 4 <= SN; s += 4) {
        u32x4 v0 = *(const u32x4*)(xbB + boff[sub][s]     + cbyte);
        u32x4 v1 = *(const u32x4*)(xbB + boff[sub][s + 1] + cbyte);
        u32x4 v2 = *(const u32x4*)(xbB + boff[sub][s + 2] + cbyte);
        u32x4 v3 = *(const u32x4*)(xbB + boff[sub][s + 3] + cbyte);
        float w0 = wgt[sub][h][s],     w1 = wgt[sub][h][s + 1];
        float w2 = wgt[sub][h][s + 2], w3 = wgt[sub][h][s + 3];
        GFMA(v0, w0); GFMA(v1, w1); GFMA(v2, w2); GFMA(v3, w3);
    }
    for (; s < SN; ++s) {
        u32x4 v = *(const u32x4*)(xbB + boff[sub][s] + cbyte);
        float w = wgt[sub][h][s];
        GFMA(v, w);
    }
    #undef GFMA

    u16x8 o;
    o[0]=f2b(a0); o[1]=f2b(a1); o[2]=f2b(a2); o[3]=f2b(a3);
    o[4]=f2b(a4); o[5]=f2b(a5); o[6]=f2b(a6); o[7]=f2b(a7);
    *(u16x8*)(out + (size_t)t * CDIM + lt * 8) = o;
}

// ---------------------------------------------------------------------------
extern "C" void kernel_launch(void* const* d_in, const int* in_sizes, int n_in,
                              void* d_out, int out_size, void* d_ws, size_t ws_size,
                              hipStream_t stream)
{
    const float* x       = (const float*)d_in[0];
    const float* wave_w  = (const float*)d_in[1];
    const float* wave_b  = (const float*)d_in[2];
    const float* query_w = (const float*)d_in[3];
    const float* query_b = (const float*)d_in[4];
    const float* key_w   = (const float*)d_in[5];
    const float* out_w   = (const float*)d_in[6];
    const float* se1_w   = (const float*)d_in[7];
    const float* se1_b   = (const float*)d_in[8];
    const float* se2_w   = (const float*)d_in[9];
    const float* se2_b   = (const float*)d_in[10];

    char* wsb = (char*)d_ws;
    u16* q_bf    = (u16*)wsb;           wsb += (size_t)NTOK * 128 * 2;
    float* freq  = (float*)wsb;         wsb += (size_t)NTOK * HN * 4;
    float* decay = (float*)wsb;         wsb += (size_t)NTOK * HN * 4;
    float* favg  = (float*)wsb;         wsb += (size_t)NTOK * 4;
    float* pavg  = (float*)wsb;         wsb += (size_t)NTOK * 4;
    u16* x_bf    = (u16*)wsb;           wsb += (size_t)NTOK * CDIM * 2;
    u16* conv_bf = (u16*)wsb;           wsb += (size_t)NTOK * CDIM * 2;
    u16* tmp1_bf = (u16*)wsb;           wsb += (size_t)NTOK * 256 * 2;
    u16* g_bf    = (u16*)wsb;           wsb += (size_t)NTOK * CDIM * 2;
    u16* qw_bf   = (u16*)wsb;           wsb += (size_t)128 * CDIM * 2;
    u16* se1w_bf = (u16*)wsb;           wsb += (size_t)256 * CDIM * 2;
    u16* se2w_bf = (u16*)wsb;           wsb += (size_t)CDIM * 256 * 2;
    u16* outw_bf = (u16*)wsb;           wsb += (size_t)CDIM * CDIM * 2;

    // All 4 weight preps in one launch
    transcast_all<<<1664, 256, 0, stream>>>(
        query_w, se1_w, se2_w, out_w, qw_bf, se1w_bf, se2w_bf, outw_bf);

    // Wave projection (exact fp32, bit-identical order) + stats + fused xcast
    wave_kernel<<<NTOK / 8, 256, 0, stream>>>(
        x, wave_w, wave_b, x_bf, freq, decay, favg, pavg);

    // QPROJ: silu(x @ query_w + b) -> q (bf16)
    mfma_gemm<1, 1><<<dim3(NTOK / 32, 1), 256, 0, stream>>>(
        x_bf, qw_bf, query_b, nullptr, q_bf, NTOK, 128, CDIM);

    // Adaptive conv -> conv (bf16)
    adaptconv_kernel<<<NTOK / 2, 256, 0, stream>>>(
        x_bf, key_w, q_bf, freq, decay, favg, pavg, conv_bf);

    // SE1: silu(conv @ se1_w + b) -> tmp1 (bf16)
    mfma_gemm<1, 1><<<dim3(NTOK / 32, 256 / 128), 256, 0, stream>>>(
        conv_bf, se1w_bf, se1_b, nullptr, tmp1_bf, NTOK, 256, CDIM);

    // SE2: sigmoid(tmp1 @ se2_w + b) * conv -> g (bf16)
    mfma_gemm<2, 0><<<dim3(NTOK / 128, CDIM / 128), 256, 0, stream>>>(
        tmp1_bf, se2w_bf, se2_b, conv_bf, g_bf, NTOK, CDIM, 256);

    // OUT: silu(g @ out_w) -> d_out (f32)
    mfma_gemm<3, 0><<<dim3(NTOK / 128, CDIM / 128), 256, 0, stream>>>(
        g_bf, outw_bf, nullptr, nullptr, d_out, NTOK, CDIM, CDIM);
}